// Round 3
// baseline (731.960 us; speedup 1.0000x reference)
//
#include <hip/hip_runtime.h>
#include <hip/hip_bf16.h>

#define Bc 8
#define Sc 2048
#define Hc 8
#define Dc 64
#define Ec 512
#define NTc 64
#define Tc (Bc*Sc)
#define N1c (4*Hc*Dc)
#define HISTc (Sc - NTc)

typedef float f32x4 __attribute__((ext_vector_type(4)));
typedef __bf16 bf16x8 __attribute__((ext_vector_type(8)));
typedef short short8 __attribute__((ext_vector_type(8)));
typedef short s4v __attribute__((ext_vector_type(4)));

__device__ __forceinline__ unsigned short f2bf(float f){
  unsigned int u = __float_as_uint(f);
  u += 0x7fffu + ((u >> 16) & 1u);
  return (unsigned short)(u >> 16);
}
__device__ __forceinline__ float silu_f(float x){
  return x * __builtin_amdgcn_rcpf(1.f + __expf(-x));
}
__device__ __forceinline__ bf16x8 ldb8(const unsigned short* p){
  return __builtin_bit_cast(bf16x8, *(const short8*)p);
}
__device__ __forceinline__ f32x4 mfma16(bf16x8 a, bf16x8 b, f32x4 c){
  return __builtin_amdgcn_mfma_f32_16x16x32_bf16(a, b, c, 0, 0, 0);
}

// ---------------- transpose + cast fp32 -> bf16 : out[c][r] = in[r][c] ----------------
__global__ __launch_bounds__(1024) void k_transpose_cast(const float* __restrict__ in,
                                                         unsigned short* __restrict__ out,
                                                         int R, int C){
  __shared__ float tile[32][33];
  int tx = threadIdx.x, ty = threadIdx.y;
  int c0 = blockIdx.x * 32, r0 = blockIdx.y * 32;
  tile[ty][tx] = in[(size_t)(r0 + ty) * C + c0 + tx];
  __syncthreads();
  out[(size_t)(c0 + ty) * R + r0 + tx] = f2bf(tile[tx][ty]);
}

// ---------------- input layernorm -> bf16 (one wave per row of 512) ----------------
__global__ __launch_bounds__(256) void k_ln_in(const float* __restrict__ x, const float* __restrict__ g,
                                               const float* __restrict__ b, unsigned short* __restrict__ xn){
  int lane = threadIdx.x & 63;
  int row = blockIdx.x * 4 + (threadIdx.x >> 6);
  const float* xr = x + (size_t)row * Ec + lane * 8;
  float4 v0 = *(const float4*)xr;
  float4 v1 = *(const float4*)(xr + 4);
  float vv[8] = {v0.x, v0.y, v0.z, v0.w, v1.x, v1.y, v1.z, v1.w};
  float s = 0.f, ss = 0.f;
  #pragma unroll
  for (int j = 0; j < 8; ++j){ s += vv[j]; ss += vv[j] * vv[j]; }
  #pragma unroll
  for (int m = 1; m < 64; m <<= 1){ s += __shfl_xor(s, m); ss += __shfl_xor(ss, m); }
  float mu = s * (1.f / Ec);
  float rs = rsqrtf(ss * (1.f / Ec) - mu * mu + 1e-5f);
  int c = lane * 8;
  short8 o;
  #pragma unroll
  for (int j = 0; j < 8; ++j) o[j] = (short)f2bf((vv[j] - mu) * rs * g[c + j] + b[c + j]);
  *(short8*)(xn + (size_t)row * Ec + c) = o;
}

// ---------------- ln(attn_out) * u -> bf16 ----------------
__global__ __launch_bounds__(256) void k_ln_mul(const float* __restrict__ att, const float* __restrict__ g,
                                                const float* __restrict__ b, const float* __restrict__ u,
                                                unsigned short* __restrict__ par){
  int lane = threadIdx.x & 63;
  int row = blockIdx.x * 4 + (threadIdx.x >> 6);
  const float* xr = att + (size_t)row * Ec + lane * 8;
  float4 v0 = *(const float4*)xr;
  float4 v1 = *(const float4*)(xr + 4);
  const float* ur = u + (size_t)row * Ec + lane * 8;
  float4 u0 = *(const float4*)ur;
  float4 u1 = *(const float4*)(ur + 4);
  float vv[8] = {v0.x, v0.y, v0.z, v0.w, v1.x, v1.y, v1.z, v1.w};
  float uu[8] = {u0.x, u0.y, u0.z, u0.w, u1.x, u1.y, u1.z, u1.w};
  float s = 0.f, ss = 0.f;
  #pragma unroll
  for (int j = 0; j < 8; ++j){ s += vv[j]; ss += vv[j] * vv[j]; }
  #pragma unroll
  for (int m = 1; m < 64; m <<= 1){ s += __shfl_xor(s, m); ss += __shfl_xor(ss, m); }
  float mu = s * (1.f / Ec);
  float rs = rsqrtf(ss * (1.f / Ec) - mu * mu + 1e-5f);
  int c = lane * 8;
  short8 o;
  #pragma unroll
  for (int j = 0; j < 8; ++j) o[j] = (short)f2bf(uu[j] * ((vv[j] - mu) * rs * g[c + j] + b[c + j]));
  *(short8*)(par + (size_t)row * Ec + c) = o;
}

// ---------------- GEMM1: mixed = silu(xn @ w_uvqk + b); scatter u,v^T,q,k ----------------
// q is pre-scaled by alpha=0.125 (exact pow2, folded out of attention inner loop).
__global__ __launch_bounds__(256) void k_gemm_uvqk(const unsigned short* __restrict__ A,
                                                   const unsigned short* __restrict__ BT,
                                                   const float* __restrict__ bias,
                                                   float* __restrict__ u_out,
                                                   unsigned short* __restrict__ vT,
                                                   unsigned short* __restrict__ qb,
                                                   unsigned short* __restrict__ kb){
  int lane = threadIdx.x & 63;
  int lm = lane & 15, quad = lane >> 4;
  int w = threadIdx.x >> 6;
  int n0 = blockIdx.x * 64;
  int m0 = blockIdx.y * 128 + w * 32;
  const unsigned short* a0p = A + (size_t)(m0 + lm) * Ec + quad * 8;
  const unsigned short* a1p = a0p + 16 * Ec;
  const unsigned short* bp0 = BT + (size_t)(n0 + lm) * Ec + quad * 8;
  f32x4 acc[2][4] = {};
  #pragma unroll 4
  for (int k0 = 0; k0 < Ec; k0 += 32){
    bf16x8 a0 = ldb8(a0p + k0);
    bf16x8 a1 = ldb8(a1p + k0);
    #pragma unroll
    for (int t = 0; t < 4; ++t){
      bf16x8 bb = ldb8(bp0 + (size_t)t * 16 * Ec + k0);
      acc[0][t] = mfma16(a0, bb, acc[0][t]);
      acc[1][t] = mfma16(a1, bb, acc[1][t]);
    }
  }
  #pragma unroll
  for (int t = 0; t < 4; ++t){
    int col = n0 + t * 16 + lm;
    float bv = bias[col];
    int cat = col >> 9;
    int c = col & 511, h = c >> 6, d = c & 63;
    #pragma unroll
    for (int i = 0; i < 2; ++i){
      #pragma unroll
      for (int r = 0; r < 4; ++r){
        int row = m0 + i * 16 + quad * 4 + r;
        float val = silu_f(acc[i][t][r] + bv);
        if (cat == 0){
          u_out[(size_t)row * Ec + col] = val;
        } else {
          int bb_ = row >> 11, s = row & (Sc - 1);
          unsigned short hv = f2bf(cat == 2 ? val * 0.125f : val);
          if (cat == 1)      vT[((size_t)(bb_ * Hc + h) * Dc + d) * Sc + s] = hv;
          else if (cat == 2) qb[((size_t)(bb_ * Hc + h) * Sc + s) * Dc + d] = hv;
          else               kb[((size_t)(bb_ * Hc + h) * Sc + s) * Dc + d] = hv;
        }
      }
    }
  }
}

// ---------------- HSTU silu attention (all-register P, no LDS) ----------------
// grid (B*H, S/64); 4 waves, wave = 16 q rows.
// Step 1: S^T = mfma_16x16x32(A=K, B=Q): lane holds P[q=lm][key=quad*4+r].
// That IS the 16x16x16 A-fragment layout (A[m=lm][k=quad*4+j]), so
// Step 2: O = mfma_16x16x16bf16_1k(A=P_regs, B=V_frag) with V_frag = 4
// consecutive bf16 from vT[d][s] (8-byte load). Zero LDS, short dep chain.
// Hot loop is mask-free: full tiles are key0 < min(qrow, HISTc); the only
// masked tile is the diagonal (key0 == qrow); tiles in [HISTc, qrow) are
// entirely zero (targets are keys only for themselves) and skipped.
__global__ __launch_bounds__(256) void k_attn(const unsigned short* __restrict__ qb,
                                              const unsigned short* __restrict__ kb,
                                              const unsigned short* __restrict__ vT,
                                              float* __restrict__ att){
  int lane = threadIdx.x & 63, w = threadIdx.x >> 6;
  int lm = lane & 15, quad = lane >> 4;
  int bh = blockIdx.x;
  int qrow = blockIdx.y * 64 + w * 16;
  const unsigned short* qp = qb + ((size_t)bh * Sc + qrow + lm) * Dc + quad * 8;
  bf16x8 qa0 = ldb8(qp), qa1 = ldb8(qp + 32);
  const unsigned short* kbp = kb + (size_t)bh * Sc * Dc;
  const unsigned short* vbp = vT + (size_t)bh * Dc * Sc;
  f32x4 o[4] = {};
  int nfull = (qrow < HISTc ? qrow : HISTc) >> 4;
  #pragma unroll 2
  for (int kt = 0; kt < nfull; ++kt){
    int key0 = kt * 16;
    const unsigned short* kp = kbp + (size_t)(key0 + lm) * Dc + quad * 8;
    f32x4 s0 = {0.f, 0.f, 0.f, 0.f};
    s0 = mfma16(ldb8(kp), qa0, s0);
    s0 = mfma16(ldb8(kp + 32), qa1, s0);
    s4v pf;
    #pragma unroll
    for (int r = 0; r < 4; ++r) pf[r] = (short)f2bf(silu_f(s0[r]));
    #pragma unroll
    for (int t = 0; t < 4; ++t){
      s4v vf = *(const s4v*)(vbp + (size_t)(t * 16 + lm) * Sc + key0 + quad * 4);
      o[t] = __builtin_amdgcn_mfma_f32_16x16x16bf16_1k(pf, vf, o[t], 0, 0, 0);
    }
  }
  { // diagonal tile key0 == qrow (the only masked tile)
    int key0 = qrow;
    const unsigned short* kp = kbp + (size_t)(key0 + lm) * Dc + quad * 8;
    f32x4 s0 = {0.f, 0.f, 0.f, 0.f};
    s0 = mfma16(ldb8(kp), qa0, s0);
    s0 = mfma16(ldb8(kp + 32), qa1, s0);
    int qg = qrow + lm;
    s4v pf;
    #pragma unroll
    for (int r = 0; r < 4; ++r){
      int kg = key0 + quad * 4 + r;
      bool ok = (kg <= qg) && ((kg < HISTc) || (kg == qg));
      pf[r] = ok ? (short)f2bf(silu_f(s0[r])) : (short)0;
    }
    #pragma unroll
    for (int t = 0; t < 4; ++t){
      s4v vf = *(const s4v*)(vbp + (size_t)(t * 16 + lm) * Sc + key0 + quad * 4);
      o[t] = __builtin_amdgcn_mfma_f32_16x16x16bf16_1k(pf, vf, o[t], 0, 0, 0);
    }
  }
  int bb_ = bh >> 3, hh = bh & 7;
  #pragma unroll
  for (int t = 0; t < 4; ++t){
    int d = t * 16 + lm;
    #pragma unroll
    for (int r = 0; r < 4; ++r){
      int s = qrow + quad * 4 + r;
      att[((size_t)(bb_ * Sc + s) * Hc + hh) * Dc + d] = o[t][r] * (1.f / Sc);
    }
  }
}

// ---------------- GEMM2: out = par @ w_proj + x ----------------
__global__ __launch_bounds__(256) void k_gemm_proj(const unsigned short* __restrict__ A,
                                                   const unsigned short* __restrict__ BT,
                                                   const float* __restrict__ x,
                                                   float* __restrict__ out){
  int lane = threadIdx.x & 63;
  int lm = lane & 15, quad = lane >> 4;
  int w = threadIdx.x >> 6;
  int n0 = blockIdx.x * 64;
  int m0 = blockIdx.y * 128 + w * 32;
  const unsigned short* a0p = A + (size_t)(m0 + lm) * Ec + quad * 8;
  const unsigned short* a1p = a0p + 16 * Ec;
  const unsigned short* bp0 = BT + (size_t)(n0 + lm) * Ec + quad * 8;
  f32x4 acc[2][4] = {};
  #pragma unroll 4
  for (int k0 = 0; k0 < Ec; k0 += 32){
    bf16x8 a0 = ldb8(a0p + k0);
    bf16x8 a1 = ldb8(a1p + k0);
    #pragma unroll
    for (int t = 0; t < 4; ++t){
      bf16x8 bb = ldb8(bp0 + (size_t)t * 16 * Ec + k0);
      acc[0][t] = mfma16(a0, bb, acc[0][t]);
      acc[1][t] = mfma16(a1, bb, acc[1][t]);
    }
  }
  #pragma unroll
  for (int t = 0; t < 4; ++t){
    int col = n0 + t * 16 + lm;
    #pragma unroll
    for (int i = 0; i < 2; ++i){
      #pragma unroll
      for (int r = 0; r < 4; ++r){
        int row = m0 + i * 16 + quad * 4 + r;
        out[(size_t)row * Ec + col] = acc[i][t][r] + x[(size_t)row * Ec + col];
      }
    }
  }
}

extern "C" void kernel_launch(void* const* d_in, const int* in_sizes, int n_in,
                              void* d_out, int out_size, void* d_ws, size_t ws_size,
                              hipStream_t stream){
  (void)in_sizes; (void)n_in; (void)out_size; (void)ws_size;
  const float* x        = (const float*)d_in[0];
  const float* w_uvqk   = (const float*)d_in[1];
  const float* b_uvqk   = (const float*)d_in[2];
  const float* ln_in_w  = (const float*)d_in[3];
  const float* ln_in_b  = (const float*)d_in[4];
  const float* ln_out_w = (const float*)d_in[5];
  const float* ln_out_b = (const float*)d_in[6];
  const float* w_proj   = (const float*)d_in[7];
  float* out = (float*)d_out;

  char* ws = (char*)d_ws;
  unsigned short* xn  = (unsigned short*)(ws + 0);          // 16 MB, reused as `par` later
  unsigned short* wuT = (unsigned short*)(ws + 16777216);   // 2 MB
  unsigned short* wpT = (unsigned short*)(ws + 18874368);   // 0.5 MB
  float*          ub  = (float*)(ws + 19398656);            // 32 MB
  unsigned short* qbf = (unsigned short*)(ws + 52953088);   // 16 MB
  unsigned short* kbf = (unsigned short*)(ws + 69730304);   // 16 MB
  unsigned short* vTt = (unsigned short*)(ws + 86507520);   // 16 MB
  float*          att = (float*)(ws + 103284736);           // 32 MB (ends 136,839,168)

  dim3 tb(32, 32);
  k_transpose_cast<<<dim3(N1c / 32, Ec / 32), tb, 0, stream>>>(w_uvqk, wuT, Ec, N1c);
  k_transpose_cast<<<dim3(Ec / 32, Ec / 32), tb, 0, stream>>>(w_proj, wpT, Ec, Ec);
  k_ln_in<<<Tc / 4, 256, 0, stream>>>(x, ln_in_w, ln_in_b, xn);
  k_gemm_uvqk<<<dim3(N1c / 64, Tc / 128), 256, 0, stream>>>(xn, wuT, b_uvqk, ub, vTt, qbf, kbf);
  k_attn<<<dim3(Bc * Hc, Sc / 64), 256, 0, stream>>>(qbf, kbf, vTt, att);
  k_ln_mul<<<Tc / 4, 256, 0, stream>>>(att, ln_out_w, ln_out_b, ub, xn);
  k_gemm_proj<<<dim3(Ec / 64, Tc / 128), 256, 0, stream>>>(xn, wpT, x, out);
}

// Round 4
// 442.961 us; speedup vs baseline: 1.6524x; 1.6524x over previous
//
#include <hip/hip_runtime.h>
#include <hip/hip_bf16.h>

#define Bc 8
#define Sc 2048
#define Hc 8
#define Dc 64
#define Ec 512
#define NTc 64
#define Tc (Bc*Sc)
#define N1c (4*Hc*Dc)
#define HISTc (Sc - NTc)

typedef float f32x4 __attribute__((ext_vector_type(4)));
typedef __bf16 bf16x8 __attribute__((ext_vector_type(8)));
typedef short short8 __attribute__((ext_vector_type(8)));
typedef short s4v __attribute__((ext_vector_type(4)));

__device__ __forceinline__ unsigned short f2bf(float f){
  unsigned int u = __float_as_uint(f);
  u += 0x7fffu + ((u >> 16) & 1u);
  return (unsigned short)(u >> 16);
}
__device__ __forceinline__ float silu_f(float x){
  return x * __builtin_amdgcn_rcpf(1.f + __expf(-x));
}
__device__ __forceinline__ bf16x8 ldb8(const unsigned short* p){
  return __builtin_bit_cast(bf16x8, *(const short8*)p);
}
__device__ __forceinline__ f32x4 mfma16(bf16x8 a, bf16x8 b, f32x4 c){
  return __builtin_amdgcn_mfma_f32_16x16x32_bf16(a, b, c, 0, 0, 0);
}
__device__ __forceinline__ void gl_lds16(const void* g, void* l){
  __builtin_amdgcn_global_load_lds((const __attribute__((address_space(1))) unsigned int*)g,
                                   (__attribute__((address_space(3))) unsigned int*)l, 16, 0, 0);
}

// ---------------- transpose + cast fp32 -> bf16 : out[c][r] = in[r][c] ----------------
__global__ __launch_bounds__(1024) void k_transpose_cast(const float* __restrict__ in,
                                                         unsigned short* __restrict__ out,
                                                         int R, int C){
  __shared__ float tile[32][33];
  int tx = threadIdx.x, ty = threadIdx.y;
  int c0 = blockIdx.x * 32, r0 = blockIdx.y * 32;
  tile[ty][tx] = in[(size_t)(r0 + ty) * C + c0 + tx];
  __syncthreads();
  out[(size_t)(c0 + ty) * R + r0 + tx] = f2bf(tile[tx][ty]);
}

// ---------------- input layernorm -> bf16 (one wave per row of 512) ----------------
__global__ __launch_bounds__(256) void k_ln_in(const float* __restrict__ x, const float* __restrict__ g,
                                               const float* __restrict__ b, unsigned short* __restrict__ xn){
  int lane = threadIdx.x & 63;
  int row = blockIdx.x * 4 + (threadIdx.x >> 6);
  const float* xr = x + (size_t)row * Ec + lane * 8;
  float4 v0 = *(const float4*)xr;
  float4 v1 = *(const float4*)(xr + 4);
  float vv[8] = {v0.x, v0.y, v0.z, v0.w, v1.x, v1.y, v1.z, v1.w};
  float s = 0.f, ss = 0.f;
  #pragma unroll
  for (int j = 0; j < 8; ++j){ s += vv[j]; ss += vv[j] * vv[j]; }
  #pragma unroll
  for (int m = 1; m < 64; m <<= 1){ s += __shfl_xor(s, m); ss += __shfl_xor(ss, m); }
  float mu = s * (1.f / Ec);
  float rs = rsqrtf(ss * (1.f / Ec) - mu * mu + 1e-5f);
  int c = lane * 8;
  short8 o;
  #pragma unroll
  for (int j = 0; j < 8; ++j) o[j] = (short)f2bf((vv[j] - mu) * rs * g[c + j] + b[c + j]);
  *(short8*)(xn + (size_t)row * Ec + c) = o;
}

// ---------------- ln(attn_out) * u -> bf16 ----------------
__global__ __launch_bounds__(256) void k_ln_mul(const float* __restrict__ att, const float* __restrict__ g,
                                                const float* __restrict__ b, const float* __restrict__ u,
                                                unsigned short* __restrict__ par){
  int lane = threadIdx.x & 63;
  int row = blockIdx.x * 4 + (threadIdx.x >> 6);
  const float* xr = att + (size_t)row * Ec + lane * 8;
  float4 v0 = *(const float4*)xr;
  float4 v1 = *(const float4*)(xr + 4);
  const float* ur = u + (size_t)row * Ec + lane * 8;
  float4 u0 = *(const float4*)ur;
  float4 u1 = *(const float4*)(ur + 4);
  float vv[8] = {v0.x, v0.y, v0.z, v0.w, v1.x, v1.y, v1.z, v1.w};
  float uu[8] = {u0.x, u0.y, u0.z, u0.w, u1.x, u1.y, u1.z, u1.w};
  float s = 0.f, ss = 0.f;
  #pragma unroll
  for (int j = 0; j < 8; ++j){ s += vv[j]; ss += vv[j] * vv[j]; }
  #pragma unroll
  for (int m = 1; m < 64; m <<= 1){ s += __shfl_xor(s, m); ss += __shfl_xor(ss, m); }
  float mu = s * (1.f / Ec);
  float rs = rsqrtf(ss * (1.f / Ec) - mu * mu + 1e-5f);
  int c = lane * 8;
  short8 o;
  #pragma unroll
  for (int j = 0; j < 8; ++j) o[j] = (short)f2bf(uu[j] * ((vv[j] - mu) * rs * g[c + j] + b[c + j]));
  *(short8*)(par + (size_t)row * Ec + c) = o;
}

// ---------------- GEMM1: mixed = silu(xn @ w_uvqk + b); scatter u,v^T,q,k ----------------
// q is pre-scaled by alpha=0.125 (exact pow2, folded out of attention inner loop).
__global__ __launch_bounds__(256) void k_gemm_uvqk(const unsigned short* __restrict__ A,
                                                   const unsigned short* __restrict__ BT,
                                                   const float* __restrict__ bias,
                                                   float* __restrict__ u_out,
                                                   unsigned short* __restrict__ vT,
                                                   unsigned short* __restrict__ qb,
                                                   unsigned short* __restrict__ kb){
  int lane = threadIdx.x & 63;
  int lm = lane & 15, quad = lane >> 4;
  int w = threadIdx.x >> 6;
  int n0 = blockIdx.x * 64;
  int m0 = blockIdx.y * 128 + w * 32;
  const unsigned short* a0p = A + (size_t)(m0 + lm) * Ec + quad * 8;
  const unsigned short* a1p = a0p + 16 * Ec;
  const unsigned short* bp0 = BT + (size_t)(n0 + lm) * Ec + quad * 8;
  f32x4 acc[2][4] = {};
  #pragma unroll 4
  for (int k0 = 0; k0 < Ec; k0 += 32){
    bf16x8 a0 = ldb8(a0p + k0);
    bf16x8 a1 = ldb8(a1p + k0);
    #pragma unroll
    for (int t = 0; t < 4; ++t){
      bf16x8 bb = ldb8(bp0 + (size_t)t * 16 * Ec + k0);
      acc[0][t] = mfma16(a0, bb, acc[0][t]);
      acc[1][t] = mfma16(a1, bb, acc[1][t]);
    }
  }
  #pragma unroll
  for (int t = 0; t < 4; ++t){
    int col = n0 + t * 16 + lm;
    float bv = bias[col];
    int cat = col >> 9;
    int c = col & 511, h = c >> 6, d = c & 63;
    #pragma unroll
    for (int i = 0; i < 2; ++i){
      #pragma unroll
      for (int r = 0; r < 4; ++r){
        int row = m0 + i * 16 + quad * 4 + r;
        float val = silu_f(acc[i][t][r] + bv);
        if (cat == 0){
          u_out[(size_t)row * Ec + col] = val;
        } else {
          int bb_ = row >> 11, s = row & (Sc - 1);
          unsigned short hv = f2bf(cat == 2 ? val * 0.125f : val);
          if (cat == 1)      vT[((size_t)(bb_ * Hc + h) * Dc + d) * Sc + s] = hv;
          else if (cat == 2) qb[((size_t)(bb_ * Hc + h) * Sc + s) * Dc + d] = hv;
          else               kb[((size_t)(bb_ * Hc + h) * Sc + s) * Dc + d] = hv;
        }
      }
    }
  }
}

// ---------------- HSTU silu attention: LDS-shared K/V tiles, double-buffered ----------------
// grid (B*H, 32 reversed); 4 waves, wave = 16 q rows vs shared 64-key tiles.
// K tile (64x64 bf16, [key][d]) staged via global_load_lds (layout matches);
// V tile staged VGPR->LDS as [d][key] rows padded to 72 u16 (2-way banks = free).
// QK: S^T = mfma_x32(A=Kfrag, B=Qfrag) -> lane holds P[q=lm][key=quad*4+r],
// which IS the 16x16x16 A-frag, so PV = mfma_..._1k(P_regs, V_frag) - no transform.
// Prefetch tile kt+1 (gl_lds K + V->VGPR) before computing kt; one barrier/iter.
__global__ __launch_bounds__(256) void k_attn(const unsigned short* __restrict__ qb,
                                              const unsigned short* __restrict__ kb,
                                              const unsigned short* __restrict__ vT,
                                              float* __restrict__ att){
  __shared__ __align__(16) unsigned short Kb[2][64 * 64];
  __shared__ __align__(16) unsigned short Vb[2][64 * 72];
  int tid = threadIdx.x;
  int lane = tid & 63, w = tid >> 6;
  int lm = lane & 15, quad = lane >> 4;
  int bh = blockIdx.x;
  int qblk = 31 - blockIdx.y;              // heavy blocks first (tail balance)
  int qbase = qblk * 64;
  int qrow = qbase + w * 16;
  int lastT = qblk;
  int ntiles = lastT + 1;

  const unsigned short* kbp = kb + (size_t)bh * Sc * Dc;
  const unsigned short* vbp = vT + (size_t)bh * Dc * Sc;
  const unsigned short* qp = qb + ((size_t)bh * Sc + qrow + lm) * Dc + quad * 8;
  bf16x8 qa0 = ldb8(qp), qa1 = ldb8(qp + 32);

  int vd = tid >> 3;        // V stage: row d (0..31, +32 pass 1)
  int vc = tid & 7;         // 16B chunk in row

  { // prologue: stage tile 0
    const char* ks = (const char*)kbp;
    gl_lds16(ks + tid * 16,        (char*)Kb[0] + tid * 16);
    gl_lds16(ks + 4096 + tid * 16, (char*)Kb[0] + 4096 + tid * 16);
    float4 v0 = *(const float4*)(vbp + (size_t)vd * Sc + vc * 8);
    float4 v1 = *(const float4*)(vbp + (size_t)(vd + 32) * Sc + vc * 8);
    *(float4*)(Vb[0] + vd * 72 + vc * 8) = v0;
    *(float4*)(Vb[0] + (vd + 32) * 72 + vc * 8) = v1;
  }
  __syncthreads();

  f32x4 o[4] = {};
  int qg = qrow + lm;
  for (int kt = 0; kt < ntiles; ++kt){
    int cur = kt & 1, nb = cur ^ 1;
    bool pre = (kt + 1 < ntiles);
    float4 pv0, pv1;
    if (pre){
      int kn = (kt + 1) * 64;
      const char* ks = (const char*)kbp + (size_t)kn * 128;
      gl_lds16(ks + tid * 16,        (char*)Kb[nb] + tid * 16);
      gl_lds16(ks + 4096 + tid * 16, (char*)Kb[nb] + 4096 + tid * 16);
      pv0 = *(const float4*)(vbp + (size_t)vd * Sc + kn + vc * 8);
      pv1 = *(const float4*)(vbp + (size_t)(vd + 32) * Sc + kn + vc * 8);
    }
    const unsigned short* Kc = Kb[cur];
    const unsigned short* Vc = Vb[cur];
    bool maskT = (kt == lastT);
    int key0 = kt * 64;
    #pragma unroll
    for (int s = 0; s < 4; ++s){
      bf16x8 kf0 = ldb8(Kc + (s * 16 + lm) * 64 + quad * 8);
      bf16x8 kf1 = ldb8(Kc + (s * 16 + lm) * 64 + 32 + quad * 8);
      f32x4 sc = {0.f, 0.f, 0.f, 0.f};
      sc = mfma16(kf0, qa0, sc);
      sc = mfma16(kf1, qa1, sc);
      s4v pf;
      if (maskT){
        #pragma unroll
        for (int r = 0; r < 4; ++r){
          int kg = key0 + s * 16 + quad * 4 + r;
          bool ok = (kg <= qg) && ((kg < HISTc) || (kg == qg));
          pf[r] = ok ? (short)f2bf(silu_f(sc[r])) : (short)0;
        }
      } else {
        #pragma unroll
        for (int r = 0; r < 4; ++r) pf[r] = (short)f2bf(silu_f(sc[r]));
      }
      #pragma unroll
      for (int t = 0; t < 4; ++t){
        s4v vf = *(const s4v*)(Vc + (t * 16 + lm) * 72 + s * 16 + quad * 4);
        o[t] = __builtin_amdgcn_mfma_f32_16x16x16bf16_1k(pf, vf, o[t], 0, 0, 0);
      }
    }
    if (pre){
      *(float4*)(Vb[nb] + vd * 72 + vc * 8) = pv0;
      *(float4*)(Vb[nb] + (vd + 32) * 72 + vc * 8) = pv1;
    }
    __syncthreads();
  }
  int bb_ = bh >> 3, hh = bh & 7;
  #pragma unroll
  for (int t = 0; t < 4; ++t){
    int d = t * 16 + lm;
    #pragma unroll
    for (int r = 0; r < 4; ++r){
      int s = qrow + quad * 4 + r;
      att[((size_t)(bb_ * Sc + s) * Hc + hh) * Dc + d] = o[t][r] * (1.f / Sc);
    }
  }
}

// ---------------- GEMM2: out = par @ w_proj + x ----------------
__global__ __launch_bounds__(256) void k_gemm_proj(const unsigned short* __restrict__ A,
                                                   const unsigned short* __restrict__ BT,
                                                   const float* __restrict__ x,
                                                   float* __restrict__ out){
  int lane = threadIdx.x & 63;
  int lm = lane & 15, quad = lane >> 4;
  int w = threadIdx.x >> 6;
  int n0 = blockIdx.x * 64;
  int m0 = blockIdx.y * 128 + w * 32;
  const unsigned short* a0p = A + (size_t)(m0 + lm) * Ec + quad * 8;
  const unsigned short* a1p = a0p + 16 * Ec;
  const unsigned short* bp0 = BT + (size_t)(n0 + lm) * Ec + quad * 8;
  f32x4 acc[2][4] = {};
  #pragma unroll 4
  for (int k0 = 0; k0 < Ec; k0 += 32){
    bf16x8 a0 = ldb8(a0p + k0);
    bf16x8 a1 = ldb8(a1p + k0);
    #pragma unroll
    for (int t = 0; t < 4; ++t){
      bf16x8 bb = ldb8(bp0 + (size_t)t * 16 * Ec + k0);
      acc[0][t] = mfma16(a0, bb, acc[0][t]);
      acc[1][t] = mfma16(a1, bb, acc[1][t]);
    }
  }
  #pragma unroll
  for (int t = 0; t < 4; ++t){
    int col = n0 + t * 16 + lm;
    #pragma unroll
    for (int i = 0; i < 2; ++i){
      #pragma unroll
      for (int r = 0; r < 4; ++r){
        int row = m0 + i * 16 + quad * 4 + r;
        out[(size_t)row * Ec + col] = acc[i][t][r] + x[(size_t)row * Ec + col];
      }
    }
  }
}

extern "C" void kernel_launch(void* const* d_in, const int* in_sizes, int n_in,
                              void* d_out, int out_size, void* d_ws, size_t ws_size,
                              hipStream_t stream){
  (void)in_sizes; (void)n_in; (void)out_size; (void)ws_size;
  const float* x        = (const float*)d_in[0];
  const float* w_uvqk   = (const float*)d_in[1];
  const float* b_uvqk   = (const float*)d_in[2];
  const float* ln_in_w  = (const float*)d_in[3];
  const float* ln_in_b  = (const float*)d_in[4];
  const float* ln_out_w = (const float*)d_in[5];
  const float* ln_out_b = (const float*)d_in[6];
  const float* w_proj   = (const float*)d_in[7];
  float* out = (float*)d_out;

  char* ws = (char*)d_ws;
  unsigned short* xn  = (unsigned short*)(ws + 0);          // 16 MB, reused as `par` later
  unsigned short* wuT = (unsigned short*)(ws + 16777216);   // 2 MB
  unsigned short* wpT = (unsigned short*)(ws + 18874368);   // 0.5 MB
  float*          ub  = (float*)(ws + 19398656);            // 32 MB
  unsigned short* qbf = (unsigned short*)(ws + 52953088);   // 16 MB
  unsigned short* kbf = (unsigned short*)(ws + 69730304);   // 16 MB
  unsigned short* vTt = (unsigned short*)(ws + 86507520);   // 16 MB
  float*          att = (float*)(ws + 103284736);           // 32 MB (ends 136,839,168)

  dim3 tb(32, 32);
  k_transpose_cast<<<dim3(N1c / 32, Ec / 32), tb, 0, stream>>>(w_uvqk, wuT, Ec, N1c);
  k_transpose_cast<<<dim3(Ec / 32, Ec / 32), tb, 0, stream>>>(w_proj, wpT, Ec, Ec);
  k_ln_in<<<Tc / 4, 256, 0, stream>>>(x, ln_in_w, ln_in_b, xn);
  k_gemm_uvqk<<<dim3(N1c / 64, Tc / 128), 256, 0, stream>>>(xn, wuT, b_uvqk, ub, vTt, qbf, kbf);
  k_attn<<<dim3(Bc * Hc, Sc / 64), 256, 0, stream>>>(qbf, kbf, vTt, att);
  k_ln_mul<<<Tc / 4, 256, 0, stream>>>(att, ln_out_w, ln_out_b, ub, xn);
  k_gemm_proj<<<dim3(Ec / 64, Tc / 128), 256, 0, stream>>>(xn, wpT, x, out);
}

// Round 5
// 312.699 us; speedup vs baseline: 2.3408x; 1.4166x over previous
//
#include <hip/hip_runtime.h>
#include <hip/hip_bf16.h>

#define Bc 8
#define Sc 2048
#define Hc 8
#define Dc 64
#define Ec 512
#define NTc 64
#define Tc (Bc*Sc)
#define N1c (4*Hc*Dc)
#define HISTc (Sc - NTc)

typedef float f32x4 __attribute__((ext_vector_type(4)));
typedef __bf16 bf16x8 __attribute__((ext_vector_type(8)));
typedef short short8 __attribute__((ext_vector_type(8)));
typedef short s4v __attribute__((ext_vector_type(4)));

__device__ __forceinline__ unsigned short f2bf(float f){
  unsigned int u = __float_as_uint(f);
  u += 0x7fffu + ((u >> 16) & 1u);
  return (unsigned short)(u >> 16);
}
__device__ __forceinline__ float silu_f(float x){
  return x * __builtin_amdgcn_rcpf(1.f + __expf(-x));
}
__device__ __forceinline__ bf16x8 ldb8(const unsigned short* p){
  return __builtin_bit_cast(bf16x8, *(const short8*)p);
}
__device__ __forceinline__ f32x4 mfma16(bf16x8 a, bf16x8 b, f32x4 c){
  return __builtin_amdgcn_mfma_f32_16x16x32_bf16(a, b, c, 0, 0, 0);
}
__device__ __forceinline__ void gl_lds16(const void* g, void* l){
  __builtin_amdgcn_global_load_lds((const __attribute__((address_space(1))) unsigned int*)g,
                                   (__attribute__((address_space(3))) unsigned int*)l, 16, 0, 0);
}

// ---------------- transpose + cast fp32 -> bf16 : out[c][r] = in[r][c] ----------------
__global__ __launch_bounds__(1024) void k_transpose_cast(const float* __restrict__ in,
                                                         unsigned short* __restrict__ out,
                                                         int R, int C){
  __shared__ float tile[32][33];
  int tx = threadIdx.x, ty = threadIdx.y;
  int c0 = blockIdx.x * 32, r0 = blockIdx.y * 32;
  tile[ty][tx] = in[(size_t)(r0 + ty) * C + c0 + tx];
  __syncthreads();
  out[(size_t)(c0 + ty) * R + r0 + tx] = f2bf(tile[tx][ty]);
}

// ---------------- input layernorm -> bf16 (one wave per row of 512) ----------------
__global__ __launch_bounds__(256) void k_ln_in(const float* __restrict__ x, const float* __restrict__ g,
                                               const float* __restrict__ b, unsigned short* __restrict__ xn){
  int lane = threadIdx.x & 63;
  int row = blockIdx.x * 4 + (threadIdx.x >> 6);
  const float* xr = x + (size_t)row * Ec + lane * 8;
  float4 v0 = *(const float4*)xr;
  float4 v1 = *(const float4*)(xr + 4);
  float vv[8] = {v0.x, v0.y, v0.z, v0.w, v1.x, v1.y, v1.z, v1.w};
  float s = 0.f, ss = 0.f;
  #pragma unroll
  for (int j = 0; j < 8; ++j){ s += vv[j]; ss += vv[j] * vv[j]; }
  #pragma unroll
  for (int m = 1; m < 64; m <<= 1){ s += __shfl_xor(s, m); ss += __shfl_xor(ss, m); }
  float mu = s * (1.f / Ec);
  float rs = rsqrtf(ss * (1.f / Ec) - mu * mu + 1e-5f);
  int c = lane * 8;
  short8 o;
  #pragma unroll
  for (int j = 0; j < 8; ++j) o[j] = (short)f2bf((vv[j] - mu) * rs * g[c + j] + b[c + j]);
  *(short8*)(xn + (size_t)row * Ec + c) = o;
}

// ---------------- ln(attn_out) * u -> bf16 ----------------
__global__ __launch_bounds__(256) void k_ln_mul(const float* __restrict__ att, const float* __restrict__ g,
                                                const float* __restrict__ b, const float* __restrict__ u,
                                                unsigned short* __restrict__ par){
  int lane = threadIdx.x & 63;
  int row = blockIdx.x * 4 + (threadIdx.x >> 6);
  const float* xr = att + (size_t)row * Ec + lane * 8;
  float4 v0 = *(const float4*)xr;
  float4 v1 = *(const float4*)(xr + 4);
  const float* ur = u + (size_t)row * Ec + lane * 8;
  float4 u0 = *(const float4*)ur;
  float4 u1 = *(const float4*)(ur + 4);
  float vv[8] = {v0.x, v0.y, v0.z, v0.w, v1.x, v1.y, v1.z, v1.w};
  float uu[8] = {u0.x, u0.y, u0.z, u0.w, u1.x, u1.y, u1.z, u1.w};
  float s = 0.f, ss = 0.f;
  #pragma unroll
  for (int j = 0; j < 8; ++j){ s += vv[j]; ss += vv[j] * vv[j]; }
  #pragma unroll
  for (int m = 1; m < 64; m <<= 1){ s += __shfl_xor(s, m); ss += __shfl_xor(ss, m); }
  float mu = s * (1.f / Ec);
  float rs = rsqrtf(ss * (1.f / Ec) - mu * mu + 1e-5f);
  int c = lane * 8;
  short8 o;
  #pragma unroll
  for (int j = 0; j < 8; ++j) o[j] = (short)f2bf(uu[j] * ((vv[j] - mu) * rs * g[c + j] + b[c + j]));
  *(short8*)(par + (size_t)row * Ec + c) = o;
}

// ---------------- GEMM1: m97-style staged K-loop ----------------
// 128x128 tile, BK=32 double-buffered LDS via global_load_lds(16B).
// 4 waves, each a 64x64 quadrant (4x4 16x16x32 accs). Epilogue: bias+silu,
// block-uniform category (BN=128 divides the 512-col u/v/q/k split),
// q pre-scaled by alpha=0.125.
__global__ __launch_bounds__(256) void k_gemm_uvqk(const unsigned short* __restrict__ A,
                                                   const unsigned short* __restrict__ BT,
                                                   const float* __restrict__ bias,
                                                   float* __restrict__ u_out,
                                                   unsigned short* __restrict__ vT,
                                                   unsigned short* __restrict__ qb,
                                                   unsigned short* __restrict__ kb){
  __shared__ __align__(16) unsigned short As[2][128 * 32];
  __shared__ __align__(16) unsigned short Bs[2][128 * 32];
  int tid = threadIdx.x;
  int lane = tid & 63, w = tid >> 6;
  int lm = lane & 15, quad = lane >> 4;
  int wm = w & 1, wn = w >> 1;
  int n0 = blockIdx.x * 128, m0 = blockIdx.y * 128;

  int srow = tid >> 2, scol = (tid & 3) * 8;
  const unsigned short* sa0 = A  + (size_t)(m0 + srow) * Ec + scol;
  const unsigned short* sb0 = BT + (size_t)(n0 + srow) * Ec + scol;
  char* da0 = (char*)As[0] + tid * 16;
  char* db0 = (char*)Bs[0] + tid * 16;

  // prologue: stage k0=0 into buf 0
  gl_lds16(sa0,            da0);
  gl_lds16(sa0 + 64 * Ec,  da0 + 4096);
  gl_lds16(sb0,            db0);
  gl_lds16(sb0 + 64 * Ec,  db0 + 4096);
  __syncthreads();

  f32x4 acc[4][4] = {};
  #pragma unroll 1
  for (int kt = 0; kt < 16; ++kt){
    int cur = kt & 1, nb = cur ^ 1;
    if (kt < 15){
      int k0 = (kt + 1) * 32;
      gl_lds16(sa0 + k0,           (char*)As[nb] + tid * 16);
      gl_lds16(sa0 + k0 + 64 * Ec, (char*)As[nb] + tid * 16 + 4096);
      gl_lds16(sb0 + k0,           (char*)Bs[nb] + tid * 16);
      gl_lds16(sb0 + k0 + 64 * Ec, (char*)Bs[nb] + tid * 16 + 4096);
    }
    const unsigned short* Ac = As[cur] + wm * 64 * 32;
    const unsigned short* Bcu = Bs[cur] + wn * 64 * 32;
    bf16x8 af[4], bfr[4];
    #pragma unroll
    for (int s = 0; s < 4; ++s) af[s]  = ldb8(Ac  + (s * 16 + lm) * 32 + quad * 8);
    #pragma unroll
    for (int t = 0; t < 4; ++t) bfr[t] = ldb8(Bcu + (t * 16 + lm) * 32 + quad * 8);
    #pragma unroll
    for (int s = 0; s < 4; ++s)
      #pragma unroll
      for (int t = 0; t < 4; ++t)
        acc[s][t] = mfma16(af[s], bfr[t], acc[s][t]);
    __syncthreads();
  }

  int cat = n0 >> 9;
  #pragma unroll
  for (int t = 0; t < 4; ++t){
    int colg = n0 + wn * 64 + t * 16 + lm;
    float bv = bias[colg];
    int c = colg & 511, h = c >> 6, d = c & 63;
    #pragma unroll
    for (int s = 0; s < 4; ++s){
      #pragma unroll
      for (int r = 0; r < 4; ++r){
        int row = m0 + wm * 64 + s * 16 + quad * 4 + r;
        float val = silu_f(acc[s][t][r] + bv);
        if (cat == 0){
          u_out[(size_t)row * Ec + c] = val;
        } else {
          int bb_ = row >> 11, sr = row & (Sc - 1);
          if (cat == 1)      vT[((size_t)(bb_ * Hc + h) * Dc + d) * Sc + sr] = f2bf(val);
          else if (cat == 2) qb[((size_t)(bb_ * Hc + h) * Sc + sr) * Dc + d] = f2bf(val * 0.125f);
          else               kb[((size_t)(bb_ * Hc + h) * Sc + sr) * Dc + d] = f2bf(val);
        }
      }
    }
  }
}

// ---------------- HSTU silu attention: LDS-shared K/V tiles, double-buffered ----------------
__global__ __launch_bounds__(256) void k_attn(const unsigned short* __restrict__ qb,
                                              const unsigned short* __restrict__ kb,
                                              const unsigned short* __restrict__ vT,
                                              float* __restrict__ att){
  __shared__ __align__(16) unsigned short Kb[2][64 * 64];
  __shared__ __align__(16) unsigned short Vb[2][64 * 72];
  int tid = threadIdx.x;
  int lane = tid & 63, w = tid >> 6;
  int lm = lane & 15, quad = lane >> 4;
  int bh = blockIdx.x;
  int qblk = 31 - blockIdx.y;              // heavy blocks first (tail balance)
  int qbase = qblk * 64;
  int qrow = qbase + w * 16;
  int lastT = qblk;
  int ntiles = lastT + 1;

  const unsigned short* kbp = kb + (size_t)bh * Sc * Dc;
  const unsigned short* vbp = vT + (size_t)bh * Dc * Sc;
  const unsigned short* qp = qb + ((size_t)bh * Sc + qrow + lm) * Dc + quad * 8;
  bf16x8 qa0 = ldb8(qp), qa1 = ldb8(qp + 32);

  int vd = tid >> 3;        // V stage: row d (0..31, +32 pass 1)
  int vc = tid & 7;         // 16B chunk in row

  { // prologue: stage tile 0
    const char* ks = (const char*)kbp;
    gl_lds16(ks + tid * 16,        (char*)Kb[0] + tid * 16);
    gl_lds16(ks + 4096 + tid * 16, (char*)Kb[0] + 4096 + tid * 16);
    float4 v0 = *(const float4*)(vbp + (size_t)vd * Sc + vc * 8);
    float4 v1 = *(const float4*)(vbp + (size_t)(vd + 32) * Sc + vc * 8);
    *(float4*)(Vb[0] + vd * 72 + vc * 8) = v0;
    *(float4*)(Vb[0] + (vd + 32) * 72 + vc * 8) = v1;
  }
  __syncthreads();

  f32x4 o[4] = {};
  int qg = qrow + lm;
  for (int kt = 0; kt < ntiles; ++kt){
    int cur = kt & 1, nb = cur ^ 1;
    bool pre = (kt + 1 < ntiles);
    float4 pv0, pv1;
    if (pre){
      int kn = (kt + 1) * 64;
      const char* ks = (const char*)kbp + (size_t)kn * 128;
      gl_lds16(ks + tid * 16,        (char*)Kb[nb] + tid * 16);
      gl_lds16(ks + 4096 + tid * 16, (char*)Kb[nb] + 4096 + tid * 16);
      pv0 = *(const float4*)(vbp + (size_t)vd * Sc + kn + vc * 8);
      pv1 = *(const float4*)(vbp + (size_t)(vd + 32) * Sc + kn + vc * 8);
    }
    const unsigned short* Kc = Kb[cur];
    const unsigned short* Vc = Vb[cur];
    bool maskT = (kt == lastT);
    int key0 = kt * 64;
    #pragma unroll
    for (int s = 0; s < 4; ++s){
      bf16x8 kf0 = ldb8(Kc + (s * 16 + lm) * 64 + quad * 8);
      bf16x8 kf1 = ldb8(Kc + (s * 16 + lm) * 64 + 32 + quad * 8);
      f32x4 sc = {0.f, 0.f, 0.f, 0.f};
      sc = mfma16(kf0, qa0, sc);
      sc = mfma16(kf1, qa1, sc);
      s4v pf;
      if (maskT){
        #pragma unroll
        for (int r = 0; r < 4; ++r){
          int kg = key0 + s * 16 + quad * 4 + r;
          bool ok = (kg <= qg) && ((kg < HISTc) || (kg == qg));
          pf[r] = ok ? (short)f2bf(silu_f(sc[r])) : (short)0;
        }
      } else {
        #pragma unroll
        for (int r = 0; r < 4; ++r) pf[r] = (short)f2bf(silu_f(sc[r]));
      }
      #pragma unroll
      for (int t = 0; t < 4; ++t){
        s4v vf = *(const s4v*)(Vc + (t * 16 + lm) * 72 + s * 16 + quad * 4);
        o[t] = __builtin_amdgcn_mfma_f32_16x16x16bf16_1k(pf, vf, o[t], 0, 0, 0);
      }
    }
    if (pre){
      *(float4*)(Vb[nb] + vd * 72 + vc * 8) = pv0;
      *(float4*)(Vb[nb] + (vd + 32) * 72 + vc * 8) = pv1;
    }
    __syncthreads();
  }
  int bb_ = bh >> 3, hh = bh & 7;
  #pragma unroll
  for (int t = 0; t < 4; ++t){
    int d = t * 16 + lm;
    #pragma unroll
    for (int r = 0; r < 4; ++r){
      int s = qrow + quad * 4 + r;
      att[((size_t)(bb_ * Sc + s) * Hc + hh) * Dc + d] = o[t][r] * (1.f / Sc);
    }
  }
}

// ---------------- GEMM2: out = par @ w_proj + x (m97-style staged) ----------------
__global__ __launch_bounds__(256) void k_gemm_proj(const unsigned short* __restrict__ A,
                                                   const unsigned short* __restrict__ BT,
                                                   const float* __restrict__ x,
                                                   float* __restrict__ out){
  __shared__ __align__(16) unsigned short As[2][128 * 32];
  __shared__ __align__(16) unsigned short Bs[2][128 * 32];
  int tid = threadIdx.x;
  int lane = tid & 63, w = tid >> 6;
  int lm = lane & 15, quad = lane >> 4;
  int wm = w & 1, wn = w >> 1;
  int n0 = blockIdx.x * 128, m0 = blockIdx.y * 128;

  int srow = tid >> 2, scol = (tid & 3) * 8;
  const unsigned short* sa0 = A  + (size_t)(m0 + srow) * Ec + scol;
  const unsigned short* sb0 = BT + (size_t)(n0 + srow) * Ec + scol;
  char* da0 = (char*)As[0] + tid * 16;
  char* db0 = (char*)Bs[0] + tid * 16;

  gl_lds16(sa0,            da0);
  gl_lds16(sa0 + 64 * Ec,  da0 + 4096);
  gl_lds16(sb0,            db0);
  gl_lds16(sb0 + 64 * Ec,  db0 + 4096);
  __syncthreads();

  f32x4 acc[4][4] = {};
  #pragma unroll 1
  for (int kt = 0; kt < 16; ++kt){
    int cur = kt & 1, nb = cur ^ 1;
    if (kt < 15){
      int k0 = (kt + 1) * 32;
      gl_lds16(sa0 + k0,           (char*)As[nb] + tid * 16);
      gl_lds16(sa0 + k0 + 64 * Ec, (char*)As[nb] + tid * 16 + 4096);
      gl_lds16(sb0 + k0,           (char*)Bs[nb] + tid * 16);
      gl_lds16(sb0 + k0 + 64 * Ec, (char*)Bs[nb] + tid * 16 + 4096);
    }
    const unsigned short* Ac = As[cur] + wm * 64 * 32;
    const unsigned short* Bcu = Bs[cur] + wn * 64 * 32;
    bf16x8 af[4], bfr[4];
    #pragma unroll
    for (int s = 0; s < 4; ++s) af[s]  = ldb8(Ac  + (s * 16 + lm) * 32 + quad * 8);
    #pragma unroll
    for (int t = 0; t < 4; ++t) bfr[t] = ldb8(Bcu + (t * 16 + lm) * 32 + quad * 8);
    #pragma unroll
    for (int s = 0; s < 4; ++s)
      #pragma unroll
      for (int t = 0; t < 4; ++t)
        acc[s][t] = mfma16(af[s], bfr[t], acc[s][t]);
    __syncthreads();
  }

  #pragma unroll
  for (int t = 0; t < 4; ++t){
    int col = n0 + wn * 64 + t * 16 + lm;
    #pragma unroll
    for (int s = 0; s < 4; ++s){
      #pragma unroll
      for (int r = 0; r < 4; ++r){
        int row = m0 + wm * 64 + s * 16 + quad * 4 + r;
        out[(size_t)row * Ec + col] = acc[s][t][r] + x[(size_t)row * Ec + col];
      }
    }
  }
}

extern "C" void kernel_launch(void* const* d_in, const int* in_sizes, int n_in,
                              void* d_out, int out_size, void* d_ws, size_t ws_size,
                              hipStream_t stream){
  (void)in_sizes; (void)n_in; (void)out_size; (void)ws_size;
  const float* x        = (const float*)d_in[0];
  const float* w_uvqk   = (const float*)d_in[1];
  const float* b_uvqk   = (const float*)d_in[2];
  const float* ln_in_w  = (const float*)d_in[3];
  const float* ln_in_b  = (const float*)d_in[4];
  const float* ln_out_w = (const float*)d_in[5];
  const float* ln_out_b = (const float*)d_in[6];
  const float* w_proj   = (const float*)d_in[7];
  float* out = (float*)d_out;

  char* ws = (char*)d_ws;
  unsigned short* xn  = (unsigned short*)(ws + 0);          // 16 MB, reused as `par` later
  unsigned short* wuT = (unsigned short*)(ws + 16777216);   // 2 MB
  unsigned short* wpT = (unsigned short*)(ws + 18874368);   // 0.5 MB
  float*          ub  = (float*)(ws + 19398656);            // 32 MB
  unsigned short* qbf = (unsigned short*)(ws + 52953088);   // 16 MB
  unsigned short* kbf = (unsigned short*)(ws + 69730304);   // 16 MB
  unsigned short* vTt = (unsigned short*)(ws + 86507520);   // 16 MB
  float*          att = (float*)(ws + 103284736);           // 32 MB (ends 136,839,168)

  dim3 tb(32, 32);
  k_transpose_cast<<<dim3(N1c / 32, Ec / 32), tb, 0, stream>>>(w_uvqk, wuT, Ec, N1c);
  k_transpose_cast<<<dim3(Ec / 32, Ec / 32), tb, 0, stream>>>(w_proj, wpT, Ec, Ec);
  k_ln_in<<<Tc / 4, 256, 0, stream>>>(x, ln_in_w, ln_in_b, xn);
  k_gemm_uvqk<<<dim3(N1c / 128, Tc / 128), 256, 0, stream>>>(xn, wuT, b_uvqk, ub, vTt, qbf, kbf);
  k_attn<<<dim3(Bc * Hc, Sc / 64), 256, 0, stream>>>(qbf, kbf, vTt, att);
  k_ln_mul<<<Tc / 4, 256, 0, stream>>>(att, ln_out_w, ln_out_b, ub, xn);
  k_gemm_proj<<<dim3(Ec / 128, Tc / 128), 256, 0, stream>>>(xn, wpT, x, out);
}

// Round 6
// 296.050 us; speedup vs baseline: 2.4724x; 1.0562x over previous
//
#include <hip/hip_runtime.h>
#include <hip/hip_bf16.h>

#define Bc 8
#define Sc 2048
#define Hc 8
#define Dc 64
#define Ec 512
#define NTc 64
#define Tc (Bc*Sc)
#define N1c (4*Hc*Dc)
#define HISTc (Sc - NTc)

typedef float f32x4 __attribute__((ext_vector_type(4)));
typedef __bf16 bf16x8 __attribute__((ext_vector_type(8)));
typedef short short8 __attribute__((ext_vector_type(8)));
typedef short s4v __attribute__((ext_vector_type(4)));

__device__ __forceinline__ unsigned short f2bf(float f){
  unsigned int u = __float_as_uint(f);
  u += 0x7fffu + ((u >> 16) & 1u);
  return (unsigned short)(u >> 16);
}
__device__ __forceinline__ float bf2f(unsigned short h){
  return __uint_as_float(((unsigned int)h) << 16);
}
__device__ __forceinline__ float silu_f(float x){
  return x * __builtin_amdgcn_rcpf(1.f + __expf(-x));
}
__device__ __forceinline__ bf16x8 ldb8(const unsigned short* p){
  return __builtin_bit_cast(bf16x8, *(const short8*)p);
}
__device__ __forceinline__ f32x4 mfma16(bf16x8 a, bf16x8 b, f32x4 c){
  return __builtin_amdgcn_mfma_f32_16x16x32_bf16(a, b, c, 0, 0, 0);
}
__device__ __forceinline__ void gl_lds16(const void* g, void* l){
  __builtin_amdgcn_global_load_lds((const __attribute__((address_space(1))) unsigned int*)g,
                                   (__attribute__((address_space(3))) unsigned int*)l, 16, 0, 0);
}

// ---------------- transpose + cast fp32 -> bf16 : out[c][r] = in[r][c] ----------------
__global__ __launch_bounds__(1024) void k_transpose_cast(const float* __restrict__ in,
                                                         unsigned short* __restrict__ out,
                                                         int R, int C){
  __shared__ float tile[32][33];
  int tx = threadIdx.x, ty = threadIdx.y;
  int c0 = blockIdx.x * 32, r0 = blockIdx.y * 32;
  tile[ty][tx] = in[(size_t)(r0 + ty) * C + c0 + tx];
  __syncthreads();
  out[(size_t)(c0 + ty) * R + r0 + tx] = f2bf(tile[tx][ty]);
}

// ---------------- input layernorm -> bf16 (one wave per row of 512) ----------------
__global__ __launch_bounds__(256) void k_ln_in(const float* __restrict__ x, const float* __restrict__ g,
                                               const float* __restrict__ b, unsigned short* __restrict__ xn){
  int lane = threadIdx.x & 63;
  int row = blockIdx.x * 4 + (threadIdx.x >> 6);
  const float* xr = x + (size_t)row * Ec + lane * 8;
  float4 v0 = *(const float4*)xr;
  float4 v1 = *(const float4*)(xr + 4);
  float vv[8] = {v0.x, v0.y, v0.z, v0.w, v1.x, v1.y, v1.z, v1.w};
  float s = 0.f, ss = 0.f;
  #pragma unroll
  for (int j = 0; j < 8; ++j){ s += vv[j]; ss += vv[j] * vv[j]; }
  #pragma unroll
  for (int m = 1; m < 64; m <<= 1){ s += __shfl_xor(s, m); ss += __shfl_xor(ss, m); }
  float mu = s * (1.f / Ec);
  float rs = rsqrtf(ss * (1.f / Ec) - mu * mu + 1e-5f);
  int c = lane * 8;
  short8 o;
  #pragma unroll
  for (int j = 0; j < 8; ++j) o[j] = (short)f2bf((vv[j] - mu) * rs * g[c + j] + b[c + j]);
  *(short8*)(xn + (size_t)row * Ec + c) = o;
}

// ---------------- ln(attn_out) * u -> bf16 (u is bf16) ----------------
__global__ __launch_bounds__(256) void k_ln_mul(const float* __restrict__ att, const float* __restrict__ g,
                                                const float* __restrict__ b, const unsigned short* __restrict__ u,
                                                unsigned short* __restrict__ par){
  int lane = threadIdx.x & 63;
  int row = blockIdx.x * 4 + (threadIdx.x >> 6);
  const float* xr = att + (size_t)row * Ec + lane * 8;
  float4 v0 = *(const float4*)xr;
  float4 v1 = *(const float4*)(xr + 4);
  short8 u8 = *(const short8*)(u + (size_t)row * Ec + lane * 8);
  float vv[8] = {v0.x, v0.y, v0.z, v0.w, v1.x, v1.y, v1.z, v1.w};
  float s = 0.f, ss = 0.f;
  #pragma unroll
  for (int j = 0; j < 8; ++j){ s += vv[j]; ss += vv[j] * vv[j]; }
  #pragma unroll
  for (int m = 1; m < 64; m <<= 1){ s += __shfl_xor(s, m); ss += __shfl_xor(ss, m); }
  float mu = s * (1.f / Ec);
  float rs = rsqrtf(ss * (1.f / Ec) - mu * mu + 1e-5f);
  int c = lane * 8;
  short8 o;
  #pragma unroll
  for (int j = 0; j < 8; ++j){
    float uu = bf2f((unsigned short)u8[j]);
    o[j] = (short)f2bf(uu * ((vv[j] - mu) * rs * g[c + j] + b[c + j]));
  }
  *(short8*)(par + (size_t)row * Ec + c) = o;
}

// ---------------- GEMM1: m97-style staged K-loop, per-category orientation ----------------
// 128x128 tile, BK=32 double-buffered LDS via global_load_lds(16B).
// cat (block-uniform, = n0>>9): 0=u, 1=v, 2=q, 3=k.
// v: original orientation -> lane holds 4 consecutive s for fixed d -> 8B stores to vT[d][s].
// u/q/k: swapped operands (C^T, the verified S^T trick) -> lane holds 4 consecutive
// cols for fixed token row -> 8B packed stores. u stored bf16. q pre-scaled 0.125.
__global__ __launch_bounds__(256) void k_gemm_uvqk(const unsigned short* __restrict__ A,
                                                   const unsigned short* __restrict__ BT,
                                                   const float* __restrict__ bias,
                                                   unsigned short* __restrict__ u_out,
                                                   unsigned short* __restrict__ vT,
                                                   unsigned short* __restrict__ qb,
                                                   unsigned short* __restrict__ kb){
  __shared__ __align__(16) unsigned short As[2][128 * 32];
  __shared__ __align__(16) unsigned short Bs[2][128 * 32];
  int tid = threadIdx.x;
  int lane = tid & 63, w = tid >> 6;
  int lm = lane & 15, quad = lane >> 4;
  int wm = w & 1, wn = w >> 1;
  int n0 = blockIdx.x * 128, m0 = blockIdx.y * 128;
  int cat = n0 >> 9;
  bool swp = (cat != 1);

  int srow = tid >> 2, scol = (tid & 3) * 8;
  const unsigned short* sa0 = A  + (size_t)(m0 + srow) * Ec + scol;
  const unsigned short* sb0 = BT + (size_t)(n0 + srow) * Ec + scol;
  char* da0 = (char*)As[0] + tid * 16;
  char* db0 = (char*)Bs[0] + tid * 16;

  gl_lds16(sa0,            da0);
  gl_lds16(sa0 + 64 * Ec,  da0 + 4096);
  gl_lds16(sb0,            db0);
  gl_lds16(sb0 + 64 * Ec,  db0 + 4096);
  __syncthreads();

  f32x4 acc[4][4] = {};
  #pragma unroll 1
  for (int kt = 0; kt < 16; ++kt){
    int cur = kt & 1, nb = cur ^ 1;
    if (kt < 15){
      int k0 = (kt + 1) * 32;
      gl_lds16(sa0 + k0,           (char*)As[nb] + tid * 16);
      gl_lds16(sa0 + k0 + 64 * Ec, (char*)As[nb] + tid * 16 + 4096);
      gl_lds16(sb0 + k0,           (char*)Bs[nb] + tid * 16);
      gl_lds16(sb0 + k0 + 64 * Ec, (char*)Bs[nb] + tid * 16 + 4096);
    }
    const unsigned short* Ac = As[cur] + wm * 64 * 32;
    const unsigned short* Bcu = Bs[cur] + wn * 64 * 32;
    bf16x8 af[4], bfr[4];
    #pragma unroll
    for (int s = 0; s < 4; ++s) af[s]  = ldb8(Ac  + (s * 16 + lm) * 32 + quad * 8);
    #pragma unroll
    for (int t = 0; t < 4; ++t) bfr[t] = ldb8(Bcu + (t * 16 + lm) * 32 + quad * 8);
    if (swp){
      #pragma unroll
      for (int s = 0; s < 4; ++s)
        #pragma unroll
        for (int t = 0; t < 4; ++t)
          acc[s][t] = mfma16(bfr[t], af[s], acc[s][t]);
    } else {
      #pragma unroll
      for (int s = 0; s < 4; ++s)
        #pragma unroll
        for (int t = 0; t < 4; ++t)
          acc[s][t] = mfma16(af[s], bfr[t], acc[s][t]);
    }
    __syncthreads();
  }

  if (cat == 1){
    // v, original: lane col = lm (d fixed), rows = quad*4+r (4 consecutive s)
    #pragma unroll
    for (int t = 0; t < 4; ++t){
      int colg = n0 + wn * 64 + t * 16 + lm;
      float bv = bias[colg];
      int c = colg & 511, h = c >> 6, d = c & 63;
      #pragma unroll
      for (int s = 0; s < 4; ++s){
        int row = m0 + wm * 64 + s * 16 + quad * 4;
        int bb_ = row >> 11, sr = row & (Sc - 1);
        s4v pv;
        #pragma unroll
        for (int r = 0; r < 4; ++r) pv[r] = (short)f2bf(silu_f(acc[s][t][r] + bv));
        *(s4v*)(vT + ((size_t)(bb_ * Hc + h) * Dc + d) * Sc + sr) = pv;
      }
    }
  } else {
    // u/q/k, swapped: lane row = lm (token), cols = quad*4+r (4 consecutive)
    #pragma unroll
    for (int s = 0; s < 4; ++s){
      int row = m0 + wm * 64 + s * 16 + lm;
      int bb_ = row >> 11, sr = row & (Sc - 1);
      #pragma unroll
      for (int t = 0; t < 4; ++t){
        int colg = n0 + wn * 64 + t * 16 + quad * 4;
        float4 bv = *(const float4*)(bias + colg);
        float v0 = silu_f(acc[s][t][0] + bv.x);
        float v1 = silu_f(acc[s][t][1] + bv.y);
        float v2 = silu_f(acc[s][t][2] + bv.z);
        float v3 = silu_f(acc[s][t][3] + bv.w);
        int c = colg & 511, h = c >> 6, d = c & 63;
        if (cat == 0){
          s4v p = {(short)f2bf(v0), (short)f2bf(v1), (short)f2bf(v2), (short)f2bf(v3)};
          *(s4v*)(u_out + (size_t)row * Ec + c) = p;
        } else if (cat == 2){
          s4v p = {(short)f2bf(v0 * 0.125f), (short)f2bf(v1 * 0.125f),
                   (short)f2bf(v2 * 0.125f), (short)f2bf(v3 * 0.125f)};
          *(s4v*)(qb + ((size_t)(bb_ * Hc + h) * Sc + sr) * Dc + d) = p;
        } else {
          s4v p = {(short)f2bf(v0), (short)f2bf(v1), (short)f2bf(v2), (short)f2bf(v3)};
          *(s4v*)(kb + ((size_t)(bb_ * Hc + h) * Sc + sr) * Dc + d) = p;
        }
      }
    }
  }
}

// ---------------- HSTU silu attention: LDS-shared K/V tiles, double-buffered ----------------
__global__ __launch_bounds__(256) void k_attn(const unsigned short* __restrict__ qb,
                                              const unsigned short* __restrict__ kb,
                                              const unsigned short* __restrict__ vT,
                                              float* __restrict__ att){
  __shared__ __align__(16) unsigned short Kb[2][64 * 64];
  __shared__ __align__(16) unsigned short Vb[2][64 * 72];
  int tid = threadIdx.x;
  int lane = tid & 63, w = tid >> 6;
  int lm = lane & 15, quad = lane >> 4;
  int bh = blockIdx.x;
  int qblk = 31 - blockIdx.y;              // heavy blocks first (tail balance)
  int qbase = qblk * 64;
  int qrow = qbase + w * 16;
  int lastT = qblk;
  int ntiles = lastT + 1;

  const unsigned short* kbp = kb + (size_t)bh * Sc * Dc;
  const unsigned short* vbp = vT + (size_t)bh * Dc * Sc;
  const unsigned short* qp = qb + ((size_t)bh * Sc + qrow + lm) * Dc + quad * 8;
  bf16x8 qa0 = ldb8(qp), qa1 = ldb8(qp + 32);

  int vd = tid >> 3;        // V stage: row d (0..31, +32 pass 1)
  int vc = tid & 7;         // 16B chunk in row

  { // prologue: stage tile 0
    const char* ks = (const char*)kbp;
    gl_lds16(ks + tid * 16,        (char*)Kb[0] + tid * 16);
    gl_lds16(ks + 4096 + tid * 16, (char*)Kb[0] + 4096 + tid * 16);
    float4 v0 = *(const float4*)(vbp + (size_t)vd * Sc + vc * 8);
    float4 v1 = *(const float4*)(vbp + (size_t)(vd + 32) * Sc + vc * 8);
    *(float4*)(Vb[0] + vd * 72 + vc * 8) = v0;
    *(float4*)(Vb[0] + (vd + 32) * 72 + vc * 8) = v1;
  }
  __syncthreads();

  f32x4 o[4] = {};
  int qg = qrow + lm;
  for (int kt = 0; kt < ntiles; ++kt){
    int cur = kt & 1, nb = cur ^ 1;
    bool pre = (kt + 1 < ntiles);
    float4 pv0, pv1;
    if (pre){
      int kn = (kt + 1) * 64;
      const char* ks = (const char*)kbp + (size_t)kn * 128;
      gl_lds16(ks + tid * 16,        (char*)Kb[nb] + tid * 16);
      gl_lds16(ks + 4096 + tid * 16, (char*)Kb[nb] + 4096 + tid * 16);
      pv0 = *(const float4*)(vbp + (size_t)vd * Sc + kn + vc * 8);
      pv1 = *(const float4*)(vbp + (size_t)(vd + 32) * Sc + kn + vc * 8);
    }
    const unsigned short* Kc = Kb[cur];
    const unsigned short* Vc = Vb[cur];
    bool maskT = (kt == lastT);
    int key0 = kt * 64;
    #pragma unroll
    for (int s = 0; s < 4; ++s){
      bf16x8 kf0 = ldb8(Kc + (s * 16 + lm) * 64 + quad * 8);
      bf16x8 kf1 = ldb8(Kc + (s * 16 + lm) * 64 + 32 + quad * 8);
      f32x4 sc = {0.f, 0.f, 0.f, 0.f};
      sc = mfma16(kf0, qa0, sc);
      sc = mfma16(kf1, qa1, sc);
      s4v pf;
      if (maskT){
        #pragma unroll
        for (int r = 0; r < 4; ++r){
          int kg = key0 + s * 16 + quad * 4 + r;
          bool ok = (kg <= qg) && ((kg < HISTc) || (kg == qg));
          pf[r] = ok ? (short)f2bf(silu_f(sc[r])) : (short)0;
        }
      } else {
        #pragma unroll
        for (int r = 0; r < 4; ++r) pf[r] = (short)f2bf(silu_f(sc[r]));
      }
      #pragma unroll
      for (int t = 0; t < 4; ++t){
        s4v vf = *(const s4v*)(Vc + (t * 16 + lm) * 72 + s * 16 + quad * 4);
        o[t] = __builtin_amdgcn_mfma_f32_16x16x16bf16_1k(pf, vf, o[t], 0, 0, 0);
      }
    }
    if (pre){
      *(float4*)(Vb[nb] + vd * 72 + vc * 8) = pv0;
      *(float4*)(Vb[nb] + (vd + 32) * 72 + vc * 8) = pv1;
    }
    __syncthreads();
  }
  int bb_ = bh >> 3, hh = bh & 7;
  #pragma unroll
  for (int t = 0; t < 4; ++t){
    int d = t * 16 + lm;
    #pragma unroll
    for (int r = 0; r < 4; ++r){
      int s = qrow + quad * 4 + r;
      att[((size_t)(bb_ * Sc + s) * Hc + hh) * Dc + d] = o[t][r] * (1.f / Sc);
    }
  }
}

// ---------------- GEMM2: out = par @ w_proj + x (staged, swapped epilogue) ----------------
__global__ __launch_bounds__(256) void k_gemm_proj(const unsigned short* __restrict__ A,
                                                   const unsigned short* __restrict__ BT,
                                                   const float* __restrict__ x,
                                                   float* __restrict__ out){
  __shared__ __align__(16) unsigned short As[2][128 * 32];
  __shared__ __align__(16) unsigned short Bs[2][128 * 32];
  int tid = threadIdx.x;
  int lane = tid & 63, w = tid >> 6;
  int lm = lane & 15, quad = lane >> 4;
  int wm = w & 1, wn = w >> 1;
  int n0 = blockIdx.x * 128, m0 = blockIdx.y * 128;

  int srow = tid >> 2, scol = (tid & 3) * 8;
  const unsigned short* sa0 = A  + (size_t)(m0 + srow) * Ec + scol;
  const unsigned short* sb0 = BT + (size_t)(n0 + srow) * Ec + scol;
  char* da0 = (char*)As[0] + tid * 16;
  char* db0 = (char*)Bs[0] + tid * 16;

  gl_lds16(sa0,            da0);
  gl_lds16(sa0 + 64 * Ec,  da0 + 4096);
  gl_lds16(sb0,            db0);
  gl_lds16(sb0 + 64 * Ec,  db0 + 4096);
  __syncthreads();

  f32x4 acc[4][4] = {};
  #pragma unroll 1
  for (int kt = 0; kt < 16; ++kt){
    int cur = kt & 1, nb = cur ^ 1;
    if (kt < 15){
      int k0 = (kt + 1) * 32;
      gl_lds16(sa0 + k0,           (char*)As[nb] + tid * 16);
      gl_lds16(sa0 + k0 + 64 * Ec, (char*)As[nb] + tid * 16 + 4096);
      gl_lds16(sb0 + k0,           (char*)Bs[nb] + tid * 16);
      gl_lds16(sb0 + k0 + 64 * Ec, (char*)Bs[nb] + tid * 16 + 4096);
    }
    const unsigned short* Ac = As[cur] + wm * 64 * 32;
    const unsigned short* Bcu = Bs[cur] + wn * 64 * 32;
    bf16x8 af[4], bfr[4];
    #pragma unroll
    for (int s = 0; s < 4; ++s) af[s]  = ldb8(Ac  + (s * 16 + lm) * 32 + quad * 8);
    #pragma unroll
    for (int t = 0; t < 4; ++t) bfr[t] = ldb8(Bcu + (t * 16 + lm) * 32 + quad * 8);
    #pragma unroll
    for (int s = 0; s < 4; ++s)
      #pragma unroll
      for (int t = 0; t < 4; ++t)
        acc[s][t] = mfma16(bfr[t], af[s], acc[s][t]);   // C^T orientation
    __syncthreads();
  }

  #pragma unroll
  for (int s = 0; s < 4; ++s){
    int row = m0 + wm * 64 + s * 16 + lm;
    #pragma unroll
    for (int t = 0; t < 4; ++t){
      int col = n0 + wn * 64 + t * 16 + quad * 4;
      float4 xr = *(const float4*)(x + (size_t)row * Ec + col);
      float4 o4 = {acc[s][t][0] + xr.x, acc[s][t][1] + xr.y,
                   acc[s][t][2] + xr.z, acc[s][t][3] + xr.w};
      *(float4*)(out + (size_t)row * Ec + col) = o4;
    }
  }
}

extern "C" void kernel_launch(void* const* d_in, const int* in_sizes, int n_in,
                              void* d_out, int out_size, void* d_ws, size_t ws_size,
                              hipStream_t stream){
  (void)in_sizes; (void)n_in; (void)out_size; (void)ws_size;
  const float* x        = (const float*)d_in[0];
  const float* w_uvqk   = (const float*)d_in[1];
  const float* b_uvqk   = (const float*)d_in[2];
  const float* ln_in_w  = (const float*)d_in[3];
  const float* ln_in_b  = (const float*)d_in[4];
  const float* ln_out_w = (const float*)d_in[5];
  const float* ln_out_b = (const float*)d_in[6];
  const float* w_proj   = (const float*)d_in[7];
  float* out = (float*)d_out;

  char* ws = (char*)d_ws;
  unsigned short* xn  = (unsigned short*)(ws + 0);          // 16 MB, reused as `par` later
  unsigned short* wuT = (unsigned short*)(ws + 16777216);   // 2 MB
  unsigned short* wpT = (unsigned short*)(ws + 18874368);   // 0.5 MB
  unsigned short* ub  = (unsigned short*)(ws + 19398656);   // 16 MB (bf16 now)
  unsigned short* qbf = (unsigned short*)(ws + 52953088);   // 16 MB
  unsigned short* kbf = (unsigned short*)(ws + 69730304);   // 16 MB
  unsigned short* vTt = (unsigned short*)(ws + 86507520);   // 16 MB
  float*          att = (float*)(ws + 103284736);           // 32 MB (ends 136,839,168)

  dim3 tb(32, 32);
  k_transpose_cast<<<dim3(N1c / 32, Ec / 32), tb, 0, stream>>>(w_uvqk, wuT, Ec, N1c);
  k_transpose_cast<<<dim3(Ec / 32, Ec / 32), tb, 0, stream>>>(w_proj, wpT, Ec, Ec);
  k_ln_in<<<Tc / 4, 256, 0, stream>>>(x, ln_in_w, ln_in_b, xn);
  k_gemm_uvqk<<<dim3(N1c / 128, Tc / 128), 256, 0, stream>>>(xn, wuT, b_uvqk, ub, vTt, qbf, kbf);
  k_attn<<<dim3(Bc * Hc, Sc / 64), 256, 0, stream>>>(qbf, kbf, vTt, att);
  k_ln_mul<<<Tc / 4, 256, 0, stream>>>(att, ln_out_w, ln_out_b, ub, xn);
  k_gemm_proj<<<dim3(Ec / 128, Tc / 128), 256, 0, stream>>>(xn, wpT, x, out);
}

// Round 7
// 281.072 us; speedup vs baseline: 2.6042x; 1.0533x over previous
//
#include <hip/hip_runtime.h>
#include <hip/hip_bf16.h>

#define Bc 8
#define Sc 2048
#define Hc 8
#define Dc 64
#define Ec 512
#define NTc 64
#define Tc (Bc*Sc)
#define N1c (4*Hc*Dc)
#define HISTc (Sc - NTc)

typedef float f32x4 __attribute__((ext_vector_type(4)));
typedef __bf16 bf16x8 __attribute__((ext_vector_type(8)));
typedef short short8 __attribute__((ext_vector_type(8)));
typedef short s4v __attribute__((ext_vector_type(4)));

__device__ __forceinline__ unsigned short f2bf(float f){
  unsigned int u = __float_as_uint(f);
  u += 0x7fffu + ((u >> 16) & 1u);
  return (unsigned short)(u >> 16);
}
__device__ __forceinline__ float bf2f(unsigned short h){
  return __uint_as_float(((unsigned int)h) << 16);
}
__device__ __forceinline__ float silu_f(float x){
  return x * __builtin_amdgcn_rcpf(1.f + __expf(-x));
}
__device__ __forceinline__ bf16x8 ldb8(const unsigned short* p){
  return __builtin_bit_cast(bf16x8, *(const short8*)p);
}
__device__ __forceinline__ f32x4 mfma16(bf16x8 a, bf16x8 b, f32x4 c){
  return __builtin_amdgcn_mfma_f32_16x16x32_bf16(a, b, c, 0, 0, 0);
}
__device__ __forceinline__ void gl_lds16(const void* g, void* l){
  __builtin_amdgcn_global_load_lds((const __attribute__((address_space(1))) unsigned int*)g,
                                   (__attribute__((address_space(3))) unsigned int*)l, 16, 0, 0);
}

// ---------------- transpose + cast fp32 -> bf16 : out[c][r] = in[r][c] ----------------
__global__ __launch_bounds__(1024) void k_transpose_cast(const float* __restrict__ in,
                                                         unsigned short* __restrict__ out,
                                                         int R, int C){
  __shared__ float tile[32][33];
  int tx = threadIdx.x, ty = threadIdx.y;
  int c0 = blockIdx.x * 32, r0 = blockIdx.y * 32;
  tile[ty][tx] = in[(size_t)(r0 + ty) * C + c0 + tx];
  __syncthreads();
  out[(size_t)(c0 + ty) * R + r0 + tx] = f2bf(tile[tx][ty]);
}

// ---------------- input layernorm -> bf16 (one wave per row of 512) ----------------
__global__ __launch_bounds__(256) void k_ln_in(const float* __restrict__ x, const float* __restrict__ g,
                                               const float* __restrict__ b, unsigned short* __restrict__ xn){
  int lane = threadIdx.x & 63;
  int row = blockIdx.x * 4 + (threadIdx.x >> 6);
  const float* xr = x + (size_t)row * Ec + lane * 8;
  float4 v0 = *(const float4*)xr;
  float4 v1 = *(const float4*)(xr + 4);
  float vv[8] = {v0.x, v0.y, v0.z, v0.w, v1.x, v1.y, v1.z, v1.w};
  float s = 0.f, ss = 0.f;
  #pragma unroll
  for (int j = 0; j < 8; ++j){ s += vv[j]; ss += vv[j] * vv[j]; }
  #pragma unroll
  for (int m = 1; m < 64; m <<= 1){ s += __shfl_xor(s, m); ss += __shfl_xor(ss, m); }
  float mu = s * (1.f / Ec);
  float rs = rsqrtf(ss * (1.f / Ec) - mu * mu + 1e-5f);
  int c = lane * 8;
  short8 o;
  #pragma unroll
  for (int j = 0; j < 8; ++j) o[j] = (short)f2bf((vv[j] - mu) * rs * g[c + j] + b[c + j]);
  *(short8*)(xn + (size_t)row * Ec + c) = o;
}

// ---------------- ln(attn_out) * u -> bf16 (u is bf16) ----------------
__global__ __launch_bounds__(256) void k_ln_mul(const float* __restrict__ att, const float* __restrict__ g,
                                                const float* __restrict__ b, const unsigned short* __restrict__ u,
                                                unsigned short* __restrict__ par){
  int lane = threadIdx.x & 63;
  int row = blockIdx.x * 4 + (threadIdx.x >> 6);
  const float* xr = att + (size_t)row * Ec + lane * 8;
  float4 v0 = *(const float4*)xr;
  float4 v1 = *(const float4*)(xr + 4);
  short8 u8 = *(const short8*)(u + (size_t)row * Ec + lane * 8);
  float vv[8] = {v0.x, v0.y, v0.z, v0.w, v1.x, v1.y, v1.z, v1.w};
  float s = 0.f, ss = 0.f;
  #pragma unroll
  for (int j = 0; j < 8; ++j){ s += vv[j]; ss += vv[j] * vv[j]; }
  #pragma unroll
  for (int m = 1; m < 64; m <<= 1){ s += __shfl_xor(s, m); ss += __shfl_xor(ss, m); }
  float mu = s * (1.f / Ec);
  float rs = rsqrtf(ss * (1.f / Ec) - mu * mu + 1e-5f);
  int c = lane * 8;
  short8 o;
  #pragma unroll
  for (int j = 0; j < 8; ++j){
    float uu = bf2f((unsigned short)u8[j]);
    o[j] = (short)f2bf(uu * ((vv[j] - mu) * rs * g[c + j] + b[c + j]));
  }
  *(short8*)(par + (size_t)row * Ec + c) = o;
}

// ---------------- GEMM1: staged K-loop, XOR-swizzled LDS, per-category orientation ----------------
// LDS chunk placement: global (row r, 16B-chunk c) -> chunk index r*4 + (c ^ (r&3)).
// Staged via gl_lds with per-lane SOURCE permutation (DMA dest must stay lane-linear).
// Read applies the same XOR: 8-way bank conflicts -> 4-way.
__global__ __launch_bounds__(256) void k_gemm_uvqk(const unsigned short* __restrict__ A,
                                                   const unsigned short* __restrict__ BT,
                                                   const float* __restrict__ bias,
                                                   unsigned short* __restrict__ u_out,
                                                   unsigned short* __restrict__ vT,
                                                   unsigned short* __restrict__ qb,
                                                   unsigned short* __restrict__ kb){
  __shared__ __align__(16) unsigned short As[2][128 * 32];
  __shared__ __align__(16) unsigned short Bs[2][128 * 32];
  int tid = threadIdx.x;
  int lane = tid & 63, w = tid >> 6;
  int lm = lane & 15, quad = lane >> 4;
  int wm = w & 1, wn = w >> 1;
  int n0 = blockIdx.x * 128, m0 = blockIdx.y * 128;
  int cat = n0 >> 9;
  bool swp = (cat != 1);
  int lmx = lm & 3;

  int r0s = tid >> 2, c0s = ((tid & 3) ^ (r0s & 3)) * 16;          // instr 0: rows 0..63
  int r1s = (tid + 256) >> 2, c1s = (((tid + 256) & 3) ^ (r1s & 3)) * 16; // rows 64..127
  const char* saA0 = (const char*)(A  + (size_t)(m0 + r0s) * Ec) + c0s;
  const char* saA1 = (const char*)(A  + (size_t)(m0 + r1s) * Ec) + c1s;
  const char* saB0 = (const char*)(BT + (size_t)(n0 + r0s) * Ec) + c0s;
  const char* saB1 = (const char*)(BT + (size_t)(n0 + r1s) * Ec) + c1s;

  gl_lds16(saA0, (char*)As[0] + tid * 16);
  gl_lds16(saA1, (char*)As[0] + tid * 16 + 4096);
  gl_lds16(saB0, (char*)Bs[0] + tid * 16);
  gl_lds16(saB1, (char*)Bs[0] + tid * 16 + 4096);
  __syncthreads();

  f32x4 acc[4][4] = {};
  #pragma unroll 1
  for (int kt = 0; kt < 16; ++kt){
    int cur = kt & 1, nb = cur ^ 1;
    if (kt < 15){
      int k0 = (kt + 1) * 64;   // bytes
      gl_lds16(saA0 + k0, (char*)As[nb] + tid * 16);
      gl_lds16(saA1 + k0, (char*)As[nb] + tid * 16 + 4096);
      gl_lds16(saB0 + k0, (char*)Bs[nb] + tid * 16);
      gl_lds16(saB1 + k0, (char*)Bs[nb] + tid * 16 + 4096);
    }
    bf16x8 af[4], bfr[4];
    #pragma unroll
    for (int s = 0; s < 4; ++s)
      af[s]  = ldb8(As[cur] + ((wm * 64 + s * 16 + lm) * 4 + (quad ^ lmx)) * 8);
    #pragma unroll
    for (int t = 0; t < 4; ++t)
      bfr[t] = ldb8(Bs[cur] + ((wn * 64 + t * 16 + lm) * 4 + (quad ^ lmx)) * 8);
    if (swp){
      #pragma unroll
      for (int s = 0; s < 4; ++s)
        #pragma unroll
        for (int t = 0; t < 4; ++t)
          acc[s][t] = mfma16(bfr[t], af[s], acc[s][t]);
    } else {
      #pragma unroll
      for (int s = 0; s < 4; ++s)
        #pragma unroll
        for (int t = 0; t < 4; ++t)
          acc[s][t] = mfma16(af[s], bfr[t], acc[s][t]);
    }
    __syncthreads();
  }

  if (cat == 1){
    #pragma unroll
    for (int t = 0; t < 4; ++t){
      int colg = n0 + wn * 64 + t * 16 + lm;
      float bv = bias[colg];
      int c = colg & 511, h = c >> 6, d = c & 63;
      #pragma unroll
      for (int s = 0; s < 4; ++s){
        int row = m0 + wm * 64 + s * 16 + quad * 4;
        int bb_ = row >> 11, sr = row & (Sc - 1);
        s4v pv;
        #pragma unroll
        for (int r = 0; r < 4; ++r) pv[r] = (short)f2bf(silu_f(acc[s][t][r] + bv));
        *(s4v*)(vT + ((size_t)(bb_ * Hc + h) * Dc + d) * Sc + sr) = pv;
      }
    }
  } else {
    #pragma unroll
    for (int s = 0; s < 4; ++s){
      int row = m0 + wm * 64 + s * 16 + lm;
      int bb_ = row >> 11, sr = row & (Sc - 1);
      #pragma unroll
      for (int t = 0; t < 4; ++t){
        int colg = n0 + wn * 64 + t * 16 + quad * 4;
        float4 bv = *(const float4*)(bias + colg);
        float v0 = silu_f(acc[s][t][0] + bv.x);
        float v1 = silu_f(acc[s][t][1] + bv.y);
        float v2 = silu_f(acc[s][t][2] + bv.z);
        float v3 = silu_f(acc[s][t][3] + bv.w);
        int c = colg & 511, h = c >> 6, d = c & 63;
        if (cat == 0){
          s4v p = {(short)f2bf(v0), (short)f2bf(v1), (short)f2bf(v2), (short)f2bf(v3)};
          *(s4v*)(u_out + (size_t)row * Ec + c) = p;
        } else if (cat == 2){
          s4v p = {(short)f2bf(v0 * 0.125f), (short)f2bf(v1 * 0.125f),
                   (short)f2bf(v2 * 0.125f), (short)f2bf(v3 * 0.125f)};
          *(s4v*)(qb + ((size_t)(bb_ * Hc + h) * Sc + sr) * Dc + d) = p;
        } else {
          s4v p = {(short)f2bf(v0), (short)f2bf(v1), (short)f2bf(v2), (short)f2bf(v3)};
          *(s4v*)(kb + ((size_t)(bb_ * Hc + h) * Sc + sr) * Dc + d) = p;
        }
      }
    }
  }
}

// ---------------- HSTU silu attention: swizzled DMA K/V tiles, double-buffered ----------------
// Chunk placement (both K [key][d] and V [d][key], 64x128B rows): global (r, c) ->
// chunk r*8 + (c ^ (r&7)). Reads spread over 8 bank-spans -> 2-way (free).
__global__ __launch_bounds__(256) void k_attn(const unsigned short* __restrict__ qb,
                                              const unsigned short* __restrict__ kb,
                                              const unsigned short* __restrict__ vT,
                                              float* __restrict__ att){
  __shared__ __align__(16) unsigned short Kb[2][64 * 64];
  __shared__ __align__(16) unsigned short Vb[2][64 * 64];
  int tid = threadIdx.x;
  int lane = tid & 63, w = tid >> 6;
  int lm = lane & 15, quad = lane >> 4;
  int lmx = lm & 7;
  int bh = blockIdx.x;
  int qblk = 31 - blockIdx.y;              // heavy blocks first (tail balance)
  int qrow = qblk * 64 + w * 16;
  int lastT = qblk;
  int ntiles = lastT + 1;

  const unsigned short* kbp = kb + (size_t)bh * Sc * Dc;
  const unsigned short* vbp = vT + (size_t)bh * Dc * Sc;
  const unsigned short* qp = qb + ((size_t)bh * Sc + qrow + lm) * Dc + quad * 8;
  bf16x8 qa0 = ldb8(qp), qa1 = ldb8(qp + 32);

  // staging source offsets (swizzled): instr j covers chunk indices tid + 256*j
  int r0s = tid >> 3, c0s = ((tid & 7) ^ (r0s & 7)) * 16;
  int r1s = (tid + 256) >> 3, c1s = (((tid + 256) & 7) ^ (r1s & 7)) * 16;
  const char* kS0 = (const char*)kbp + (size_t)r0s * 128 + c0s;
  const char* kS1 = (const char*)kbp + (size_t)r1s * 128 + c1s;
  const char* vS0 = (const char*)vbp + (size_t)r0s * (Sc * 2) + c0s;
  const char* vS1 = (const char*)vbp + (size_t)r1s * (Sc * 2) + c1s;

  { // prologue: stage tile 0
    gl_lds16(kS0, (char*)Kb[0] + tid * 16);
    gl_lds16(kS1, (char*)Kb[0] + tid * 16 + 4096);
    gl_lds16(vS0, (char*)Vb[0] + tid * 16);
    gl_lds16(vS1, (char*)Vb[0] + tid * 16 + 4096);
  }
  __syncthreads();

  f32x4 o[4] = {};
  int qg = qrow + lm;
  for (int kt = 0; kt < ntiles; ++kt){
    int cur = kt & 1, nb = cur ^ 1;
    if (kt + 1 < ntiles){
      int knb = (kt + 1) * 128;   // key offset in bytes
      gl_lds16(kS0 + (size_t)(kt + 1) * 8192, (char*)Kb[nb] + tid * 16);
      gl_lds16(kS1 + (size_t)(kt + 1) * 8192, (char*)Kb[nb] + tid * 16 + 4096);
      gl_lds16(vS0 + knb, (char*)Vb[nb] + tid * 16);
      gl_lds16(vS1 + knb, (char*)Vb[nb] + tid * 16 + 4096);
    }
    const unsigned short* Kc = Kb[cur];
    const unsigned short* Vc = Vb[cur];
    bool maskT = (kt == lastT);
    int key0 = kt * 64;
    #pragma unroll
    for (int s = 0; s < 4; ++s){
      int krow = (s * 16 + lm) * 8;
      bf16x8 kf0 = ldb8(Kc + (krow + (quad ^ lmx)) * 8);
      bf16x8 kf1 = ldb8(Kc + (krow + ((quad + 4) ^ lmx)) * 8);
      f32x4 sc = {0.f, 0.f, 0.f, 0.f};
      sc = mfma16(kf0, qa0, sc);
      sc = mfma16(kf1, qa1, sc);
      s4v pf;
      if (maskT){
        #pragma unroll
        for (int r = 0; r < 4; ++r){
          int kg = key0 + s * 16 + quad * 4 + r;
          bool ok = (kg <= qg) && ((kg < HISTc) || (kg == qg));
          pf[r] = ok ? (short)f2bf(silu_f(sc[r])) : (short)0;
        }
      } else {
        #pragma unroll
        for (int r = 0; r < 4; ++r) pf[r] = (short)f2bf(silu_f(sc[r]));
      }
      #pragma unroll
      for (int t = 0; t < 4; ++t){
        int vrow = (t * 16 + lm) * 8;
        s4v vf = *(const s4v*)(Vc + (vrow + ((2 * s + (quad >> 1)) ^ lmx)) * 8 + (quad & 1) * 4);
        o[t] = __builtin_amdgcn_mfma_f32_16x16x16bf16_1k(pf, vf, o[t], 0, 0, 0);
      }
    }
    __syncthreads();
  }
  int bb_ = bh >> 3, hh = bh & 7;
  #pragma unroll
  for (int t = 0; t < 4; ++t){
    int d = t * 16 + lm;
    #pragma unroll
    for (int r = 0; r < 4; ++r){
      int s = qrow + quad * 4 + r;
      att[((size_t)(bb_ * Sc + s) * Hc + hh) * Dc + d] = o[t][r] * (1.f / Sc);
    }
  }
}

// ---------------- GEMM2: out = par @ w_proj + x (staged, swizzled, C^T epilogue) ----------------
__global__ __launch_bounds__(256) void k_gemm_proj(const unsigned short* __restrict__ A,
                                                   const unsigned short* __restrict__ BT,
                                                   const float* __restrict__ x,
                                                   float* __restrict__ out){
  __shared__ __align__(16) unsigned short As[2][128 * 32];
  __shared__ __align__(16) unsigned short Bs[2][128 * 32];
  int tid = threadIdx.x;
  int lane = tid & 63, w = tid >> 6;
  int lm = lane & 15, quad = lane >> 4;
  int wm = w & 1, wn = w >> 1;
  int n0 = blockIdx.x * 128, m0 = blockIdx.y * 128;
  int lmx = lm & 3;

  int r0s = tid >> 2, c0s = ((tid & 3) ^ (r0s & 3)) * 16;
  int r1s = (tid + 256) >> 2, c1s = (((tid + 256) & 3) ^ (r1s & 3)) * 16;
  const char* saA0 = (const char*)(A  + (size_t)(m0 + r0s) * Ec) + c0s;
  const char* saA1 = (const char*)(A  + (size_t)(m0 + r1s) * Ec) + c1s;
  const char* saB0 = (const char*)(BT + (size_t)(n0 + r0s) * Ec) + c0s;
  const char* saB1 = (const char*)(BT + (size_t)(n0 + r1s) * Ec) + c1s;

  gl_lds16(saA0, (char*)As[0] + tid * 16);
  gl_lds16(saA1, (char*)As[0] + tid * 16 + 4096);
  gl_lds16(saB0, (char*)Bs[0] + tid * 16);
  gl_lds16(saB1, (char*)Bs[0] + tid * 16 + 4096);
  __syncthreads();

  f32x4 acc[4][4] = {};
  #pragma unroll 1
  for (int kt = 0; kt < 16; ++kt){
    int cur = kt & 1, nb = cur ^ 1;
    if (kt < 15){
      int k0 = (kt + 1) * 64;   // bytes
      gl_lds16(saA0 + k0, (char*)As[nb] + tid * 16);
      gl_lds16(saA1 + k0, (char*)As[nb] + tid * 16 + 4096);
      gl_lds16(saB0 + k0, (char*)Bs[nb] + tid * 16);
      gl_lds16(saB1 + k0, (char*)Bs[nb] + tid * 16 + 4096);
    }
    bf16x8 af[4], bfr[4];
    #pragma unroll
    for (int s = 0; s < 4; ++s)
      af[s]  = ldb8(As[cur] + ((wm * 64 + s * 16 + lm) * 4 + (quad ^ lmx)) * 8);
    #pragma unroll
    for (int t = 0; t < 4; ++t)
      bfr[t] = ldb8(Bs[cur] + ((wn * 64 + t * 16 + lm) * 4 + (quad ^ lmx)) * 8);
    #pragma unroll
    for (int s = 0; s < 4; ++s)
      #pragma unroll
      for (int t = 0; t < 4; ++t)
        acc[s][t] = mfma16(bfr[t], af[s], acc[s][t]);   // C^T orientation
    __syncthreads();
  }

  #pragma unroll
  for (int s = 0; s < 4; ++s){
    int row = m0 + wm * 64 + s * 16 + lm;
    #pragma unroll
    for (int t = 0; t < 4; ++t){
      int col = n0 + wn * 64 + t * 16 + quad * 4;
      float4 xr = *(const float4*)(x + (size_t)row * Ec + col);
      float4 o4 = {acc[s][t][0] + xr.x, acc[s][t][1] + xr.y,
                   acc[s][t][2] + xr.z, acc[s][t][3] + xr.w};
      *(float4*)(out + (size_t)row * Ec + col) = o4;
    }
  }
}

extern "C" void kernel_launch(void* const* d_in, const int* in_sizes, int n_in,
                              void* d_out, int out_size, void* d_ws, size_t ws_size,
                              hipStream_t stream){
  (void)in_sizes; (void)n_in; (void)out_size; (void)ws_size;
  const float* x        = (const float*)d_in[0];
  const float* w_uvqk   = (const float*)d_in[1];
  const float* b_uvqk   = (const float*)d_in[2];
  const float* ln_in_w  = (const float*)d_in[3];
  const float* ln_in_b  = (const float*)d_in[4];
  const float* ln_out_w = (const float*)d_in[5];
  const float* ln_out_b = (const float*)d_in[6];
  const float* w_proj   = (const float*)d_in[7];
  float* out = (float*)d_out;

  char* ws = (char*)d_ws;
  unsigned short* xn  = (unsigned short*)(ws + 0);          // 16 MB, reused as `par` later
  unsigned short* wuT = (unsigned short*)(ws + 16777216);   // 2 MB
  unsigned short* wpT = (unsigned short*)(ws + 18874368);   // 0.5 MB
  unsigned short* ub  = (unsigned short*)(ws + 19398656);   // 16 MB (bf16)
  unsigned short* qbf = (unsigned short*)(ws + 52953088);   // 16 MB
  unsigned short* kbf = (unsigned short*)(ws + 69730304);   // 16 MB
  unsigned short* vTt = (unsigned short*)(ws + 86507520);   // 16 MB
  float*          att = (float*)(ws + 103284736);           // 32 MB (ends 136,839,168)

  dim3 tb(32, 32);
  k_transpose_cast<<<dim3(N1c / 32, Ec / 32), tb, 0, stream>>>(w_uvqk, wuT, Ec, N1c);
  k_transpose_cast<<<dim3(Ec / 32, Ec / 32), tb, 0, stream>>>(w_proj, wpT, Ec, Ec);
  k_ln_in<<<Tc / 4, 256, 0, stream>>>(x, ln_in_w, ln_in_b, xn);
  k_gemm_uvqk<<<dim3(N1c / 128, Tc / 128), 256, 0, stream>>>(xn, wuT, b_uvqk, ub, vTt, qbf, kbf);
  k_attn<<<dim3(Bc * Hc, Sc / 64), 256, 0, stream>>>(qbf, kbf, vTt, att);
  k_ln_mul<<<Tc / 4, 256, 0, stream>>>(att, ln_out_w, ln_out_b, ub, xn);
  k_gemm_proj<<<dim3(Ec / 128, Tc / 128), 256, 0, stream>>>(xn, wpT, x, out);
}

// Round 9
// 280.002 us; speedup vs baseline: 2.6141x; 1.0038x over previous
//
#include <hip/hip_runtime.h>
#include <hip/hip_bf16.h>

#define Bc 8
#define Sc 2048
#define Hc 8
#define Dc 64
#define Ec 512
#define NTc 64
#define Tc (Bc*Sc)
#define N1c (4*Hc*Dc)
#define HISTc (Sc - NTc)

typedef float f32x4 __attribute__((ext_vector_type(4)));
typedef __bf16 bf16x8 __attribute__((ext_vector_type(8)));
typedef short short8 __attribute__((ext_vector_type(8)));
typedef short s4v __attribute__((ext_vector_type(4)));

__device__ __forceinline__ unsigned short f2bf(float f){
  unsigned int u = __float_as_uint(f);
  u += 0x7fffu + ((u >> 16) & 1u);
  return (unsigned short)(u >> 16);
}
__device__ __forceinline__ float bf2f(unsigned short h){
  return __uint_as_float(((unsigned int)h) << 16);
}
// packed f32x2 -> bf16x2 (v_cvt_pk_bf16_f32)
__device__ __forceinline__ unsigned int pkbf(float a, float b){
  float2 f; f.x = a; f.y = b;
  __hip_bfloat162 h = __float22bfloat162_rn(f);
  unsigned int u;
  __builtin_memcpy(&u, &h, 4);
  return u;
}
__device__ __forceinline__ s4v pk4(float a, float b, float c, float d){
  uint2 u; u.x = pkbf(a, b); u.y = pkbf(c, d);
  return __builtin_bit_cast(s4v, u);
}
__device__ __forceinline__ float silu_f(float x){
  return x * __builtin_amdgcn_rcpf(1.f + __expf(-x));
}
__device__ __forceinline__ bf16x8 ldb8(const unsigned short* p){
  return __builtin_bit_cast(bf16x8, *(const short8*)p);
}
__device__ __forceinline__ f32x4 mfma16(bf16x8 a, bf16x8 b, f32x4 c){
  return __builtin_amdgcn_mfma_f32_16x16x32_bf16(a, b, c, 0, 0, 0);
}
__device__ __forceinline__ void gl_lds16(const void* g, void* l){
  __builtin_amdgcn_global_load_lds((const __attribute__((address_space(1))) unsigned int*)g,
                                   (__attribute__((address_space(3))) unsigned int*)l, 16, 0, 0);
}

// ---------------- transpose + cast fp32 -> bf16 : out[c][r] = in[r][c] ----------------
__global__ __launch_bounds__(1024) void k_transpose_cast(const float* __restrict__ in,
                                                         unsigned short* __restrict__ out,
                                                         int R, int C){
  __shared__ float tile[32][33];
  int tx = threadIdx.x, ty = threadIdx.y;
  int c0 = blockIdx.x * 32, r0 = blockIdx.y * 32;
  tile[ty][tx] = in[(size_t)(r0 + ty) * C + c0 + tx];
  __syncthreads();
  out[(size_t)(c0 + ty) * R + r0 + tx] = f2bf(tile[tx][ty]);
}

// ---------------- input layernorm -> bf16 (one wave per row of 512) ----------------
__global__ __launch_bounds__(256) void k_ln_in(const float* __restrict__ x, const float* __restrict__ g,
                                               const float* __restrict__ b, unsigned short* __restrict__ xn){
  int lane = threadIdx.x & 63;
  int row = blockIdx.x * 4 + (threadIdx.x >> 6);
  const float* xr = x + (size_t)row * Ec + lane * 8;
  float4 v0 = *(const float4*)xr;
  float4 v1 = *(const float4*)(xr + 4);
  float vv[8] = {v0.x, v0.y, v0.z, v0.w, v1.x, v1.y, v1.z, v1.w};
  float s = 0.f, ss = 0.f;
  #pragma unroll
  for (int j = 0; j < 8; ++j){ s += vv[j]; ss += vv[j] * vv[j]; }
  #pragma unroll
  for (int m = 1; m < 64; m <<= 1){ s += __shfl_xor(s, m); ss += __shfl_xor(ss, m); }
  float mu = s * (1.f / Ec);
  float rs = rsqrtf(ss * (1.f / Ec) - mu * mu + 1e-5f);
  int c = lane * 8;
  float o[8];
  #pragma unroll
  for (int j = 0; j < 8; ++j) o[j] = (vv[j] - mu) * rs * g[c + j] + b[c + j];
  uint4 pk; pk.x = pkbf(o[0], o[1]); pk.y = pkbf(o[2], o[3]);
  pk.z = pkbf(o[4], o[5]); pk.w = pkbf(o[6], o[7]);
  *(uint4*)(xn + (size_t)row * Ec + c) = pk;
}

// ---------------- ln(attn_out) * u -> bf16 (att and u are bf16) ----------------
__global__ __launch_bounds__(256) void k_ln_mul(const unsigned short* __restrict__ att, const float* __restrict__ g,
                                                const float* __restrict__ b, const unsigned short* __restrict__ u,
                                                unsigned short* __restrict__ par){
  int lane = threadIdx.x & 63;
  int row = blockIdx.x * 4 + (threadIdx.x >> 6);
  short8 a8 = *(const short8*)(att + (size_t)row * Ec + lane * 8);
  short8 u8 = *(const short8*)(u + (size_t)row * Ec + lane * 8);
  float vv[8];
  #pragma unroll
  for (int j = 0; j < 8; ++j) vv[j] = bf2f((unsigned short)a8[j]);
  float s = 0.f, ss = 0.f;
  #pragma unroll
  for (int j = 0; j < 8; ++j){ s += vv[j]; ss += vv[j] * vv[j]; }
  #pragma unroll
  for (int m = 1; m < 64; m <<= 1){ s += __shfl_xor(s, m); ss += __shfl_xor(ss, m); }
  float mu = s * (1.f / Ec);
  float rs = rsqrtf(ss * (1.f / Ec) - mu * mu + 1e-5f);
  int c = lane * 8;
  float o[8];
  #pragma unroll
  for (int j = 0; j < 8; ++j){
    float uu = bf2f((unsigned short)u8[j]);
    o[j] = uu * ((vv[j] - mu) * rs * g[c + j] + b[c + j]);
  }
  uint4 pk; pk.x = pkbf(o[0], o[1]); pk.y = pkbf(o[2], o[3]);
  pk.z = pkbf(o[4], o[5]); pk.w = pkbf(o[6], o[7]);
  *(uint4*)(par + (size_t)row * Ec + c) = pk;
}

// ---------------- GEMM1: staged K-loop, XOR-swizzled LDS, per-category orientation ----------------
__global__ __launch_bounds__(256) void k_gemm_uvqk(const unsigned short* __restrict__ A,
                                                   const unsigned short* __restrict__ BT,
                                                   const float* __restrict__ bias,
                                                   unsigned short* __restrict__ u_out,
                                                   unsigned short* __restrict__ vT,
                                                   unsigned short* __restrict__ qb,
                                                   unsigned short* __restrict__ kb){
  __shared__ __align__(16) unsigned short As[2][128 * 32];
  __shared__ __align__(16) unsigned short Bs[2][128 * 32];
  int tid = threadIdx.x;
  int lane = tid & 63, w = tid >> 6;
  int lm = lane & 15, quad = lane >> 4;
  int wm = w & 1, wn = w >> 1;
  int n0 = blockIdx.x * 128, m0 = blockIdx.y * 128;
  int cat = n0 >> 9;
  bool swp = (cat != 1);
  int lmx = lm & 3;

  int r0s = tid >> 2, c0s = ((tid & 3) ^ (r0s & 3)) * 16;
  int r1s = (tid + 256) >> 2, c1s = (((tid + 256) & 3) ^ (r1s & 3)) * 16;
  const char* saA0 = (const char*)(A  + (size_t)(m0 + r0s) * Ec) + c0s;
  const char* saA1 = (const char*)(A  + (size_t)(m0 + r1s) * Ec) + c1s;
  const char* saB0 = (const char*)(BT + (size_t)(n0 + r0s) * Ec) + c0s;
  const char* saB1 = (const char*)(BT + (size_t)(n0 + r1s) * Ec) + c1s;

  gl_lds16(saA0, (char*)As[0] + tid * 16);
  gl_lds16(saA1, (char*)As[0] + tid * 16 + 4096);
  gl_lds16(saB0, (char*)Bs[0] + tid * 16);
  gl_lds16(saB1, (char*)Bs[0] + tid * 16 + 4096);
  __syncthreads();

  f32x4 acc[4][4] = {};
  #pragma unroll 1
  for (int kt = 0; kt < 16; ++kt){
    int cur = kt & 1, nb = cur ^ 1;
    if (kt < 15){
      int k0 = (kt + 1) * 64;   // bytes
      gl_lds16(saA0 + k0, (char*)As[nb] + tid * 16);
      gl_lds16(saA1 + k0, (char*)As[nb] + tid * 16 + 4096);
      gl_lds16(saB0 + k0, (char*)Bs[nb] + tid * 16);
      gl_lds16(saB1 + k0, (char*)Bs[nb] + tid * 16 + 4096);
    }
    bf16x8 af[4], bfr[4];
    #pragma unroll
    for (int s = 0; s < 4; ++s)
      af[s]  = ldb8(As[cur] + ((wm * 64 + s * 16 + lm) * 4 + (quad ^ lmx)) * 8);
    #pragma unroll
    for (int t = 0; t < 4; ++t)
      bfr[t] = ldb8(Bs[cur] + ((wn * 64 + t * 16 + lm) * 4 + (quad ^ lmx)) * 8);
    if (swp){
      #pragma unroll
      for (int s = 0; s < 4; ++s)
        #pragma unroll
        for (int t = 0; t < 4; ++t)
          acc[s][t] = mfma16(bfr[t], af[s], acc[s][t]);
    } else {
      #pragma unroll
      for (int s = 0; s < 4; ++s)
        #pragma unroll
        for (int t = 0; t < 4; ++t)
          acc[s][t] = mfma16(af[s], bfr[t], acc[s][t]);
    }
    __syncthreads();
  }

  if (cat == 1){
    #pragma unroll
    for (int t = 0; t < 4; ++t){
      int colg = n0 + wn * 64 + t * 16 + lm;
      float bv = bias[colg];
      int c = colg & 511, h = c >> 6, d = c & 63;
      #pragma unroll
      for (int s = 0; s < 4; ++s){
        int row = m0 + wm * 64 + s * 16 + quad * 4;
        int bb_ = row >> 11, sr = row & (Sc - 1);
        s4v pv = pk4(silu_f(acc[s][t][0] + bv), silu_f(acc[s][t][1] + bv),
                     silu_f(acc[s][t][2] + bv), silu_f(acc[s][t][3] + bv));
        *(s4v*)(vT + ((size_t)(bb_ * Hc + h) * Dc + d) * Sc + sr) = pv;
      }
    }
  } else {
    #pragma unroll
    for (int s = 0; s < 4; ++s){
      int row = m0 + wm * 64 + s * 16 + lm;
      int bb_ = row >> 11, sr = row & (Sc - 1);
      #pragma unroll
      for (int t = 0; t < 4; ++t){
        int colg = n0 + wn * 64 + t * 16 + quad * 4;
        float4 bv = *(const float4*)(bias + colg);
        float v0 = silu_f(acc[s][t][0] + bv.x);
        float v1 = silu_f(acc[s][t][1] + bv.y);
        float v2 = silu_f(acc[s][t][2] + bv.z);
        float v3 = silu_f(acc[s][t][3] + bv.w);
        int c = colg & 511, h = c >> 6, d = c & 63;
        if (cat == 0){
          *(s4v*)(u_out + (size_t)row * Ec + c) = pk4(v0, v1, v2, v3);
        } else if (cat == 2){
          *(s4v*)(qb + ((size_t)(bb_ * Hc + h) * Sc + sr) * Dc + d) =
            pk4(v0 * 0.125f, v1 * 0.125f, v2 * 0.125f, v3 * 0.125f);
        } else {
          *(s4v*)(kb + ((size_t)(bb_ * Hc + h) * Sc + sr) * Dc + d) = pk4(v0, v1, v2, v3);
        }
      }
    }
  }
}

// ---------------- HSTU silu attention: swizzled DMA K/V tiles, double-buffered ----------------
__global__ __launch_bounds__(256) void k_attn(const unsigned short* __restrict__ qb,
                                              const unsigned short* __restrict__ kb,
                                              const unsigned short* __restrict__ vT,
                                              unsigned short* __restrict__ att){
  __shared__ __align__(16) unsigned short Kb[2][64 * 64];
  __shared__ __align__(16) unsigned short Vb[2][64 * 64];
  int tid = threadIdx.x;
  int lane = tid & 63, w = tid >> 6;
  int lm = lane & 15, quad = lane >> 4;
  int lmx = lm & 7;
  int bh = blockIdx.x;
  int qblk = 31 - blockIdx.y;              // heavy blocks first (tail balance)
  int qrow = qblk * 64 + w * 16;
  int lastT = qblk;
  int ntiles = lastT + 1;

  const unsigned short* kbp = kb + (size_t)bh * Sc * Dc;
  const unsigned short* vbp = vT + (size_t)bh * Dc * Sc;
  const unsigned short* qp = qb + ((size_t)bh * Sc + qrow + lm) * Dc + quad * 8;
  bf16x8 qa0 = ldb8(qp), qa1 = ldb8(qp + 32);

  int r0s = tid >> 3, c0s = ((tid & 7) ^ (r0s & 7)) * 16;
  int r1s = (tid + 256) >> 3, c1s = (((tid + 256) & 7) ^ (r1s & 7)) * 16;
  const char* kS0 = (const char*)kbp + (size_t)r0s * 128 + c0s;
  const char* kS1 = (const char*)kbp + (size_t)r1s * 128 + c1s;
  const char* vS0 = (const char*)vbp + (size_t)r0s * (Sc * 2) + c0s;
  const char* vS1 = (const char*)vbp + (size_t)r1s * (Sc * 2) + c1s;

  { // prologue: stage tile 0
    gl_lds16(kS0, (char*)Kb[0] + tid * 16);
    gl_lds16(kS1, (char*)Kb[0] + tid * 16 + 4096);
    gl_lds16(vS0, (char*)Vb[0] + tid * 16);
    gl_lds16(vS1, (char*)Vb[0] + tid * 16 + 4096);
  }
  __syncthreads();

  f32x4 o[4] = {};
  int qg = qrow + lm;
  for (int kt = 0; kt < ntiles; ++kt){
    int cur = kt & 1, nb = cur ^ 1;
    if (kt + 1 < ntiles){
      int knb = (kt + 1) * 128;   // key offset in bytes
      gl_lds16(kS0 + (size_t)(kt + 1) * 8192, (char*)Kb[nb] + tid * 16);
      gl_lds16(kS1 + (size_t)(kt + 1) * 8192, (char*)Kb[nb] + tid * 16 + 4096);
      gl_lds16(vS0 + knb, (char*)Vb[nb] + tid * 16);
      gl_lds16(vS1 + knb, (char*)Vb[nb] + tid * 16 + 4096);
    }
    const unsigned short* Kc = Kb[cur];
    const unsigned short* Vc = Vb[cur];
    bool maskT = (kt == lastT);
    int key0 = kt * 64;
    #pragma unroll
    for (int s = 0; s < 4; ++s){
      int krow = (s * 16 + lm) * 8;
      bf16x8 kf0 = ldb8(Kc + (krow + (quad ^ lmx)) * 8);
      bf16x8 kf1 = ldb8(Kc + (krow + ((quad + 4) ^ lmx)) * 8);
      f32x4 sc = {0.f, 0.f, 0.f, 0.f};
      sc = mfma16(kf0, qa0, sc);
      sc = mfma16(kf1, qa1, sc);
      s4v pf;
      if (maskT){
        float m[4];
        #pragma unroll
        for (int r = 0; r < 4; ++r){
          int kg = key0 + s * 16 + quad * 4 + r;
          bool ok = (kg <= qg) && ((kg < HISTc) || (kg == qg));
          m[r] = ok ? silu_f(sc[r]) : 0.f;
        }
        pf = pk4(m[0], m[1], m[2], m[3]);
      } else {
        pf = pk4(silu_f(sc[0]), silu_f(sc[1]), silu_f(sc[2]), silu_f(sc[3]));
      }
      #pragma unroll
      for (int t = 0; t < 4; ++t){
        int vrow = (t * 16 + lm) * 8;
        s4v vf = *(const s4v*)(Vc + (vrow + ((2 * s + (quad >> 1)) ^ lmx)) * 8 + (quad & 1) * 4);
        o[t] = __builtin_amdgcn_mfma_f32_16x16x16bf16_1k(pf, vf, o[t], 0, 0, 0);
      }
    }
    __syncthreads();
  }
  int bb_ = bh >> 3, hh = bh & 7;
  #pragma unroll
  for (int t = 0; t < 4; ++t){
    int d = t * 16 + lm;
    unsigned int p01 = pkbf(o[t][0] * (1.f / Sc), o[t][1] * (1.f / Sc));
    unsigned int p23 = pkbf(o[t][2] * (1.f / Sc), o[t][3] * (1.f / Sc));
    size_t base = ((size_t)(bb_ * Sc + qrow + quad * 4) * Hc + hh) * Dc + d;
    att[base]               = (unsigned short)p01;
    att[base + Hc * Dc]     = (unsigned short)(p01 >> 16);
    att[base + 2 * Hc * Dc] = (unsigned short)p23;
    att[base + 3 * Hc * Dc] = (unsigned short)(p23 >> 16);
  }
}

// ---------------- GEMM2: out = par @ w_proj + x (staged, swizzled, C^T epilogue) ----------------
__global__ __launch_bounds__(256) void k_gemm_proj(const unsigned short* __restrict__ A,
                                                   const unsigned short* __restrict__ BT,
                                                   const float* __restrict__ x,
                                                   float* __restrict__ out){
  __shared__ __align__(16) unsigned short As[2][128 * 32];
  __shared__ __align__(16) unsigned short Bs[2][128 * 32];
  int tid = threadIdx.x;
  int lane = tid & 63, w = tid >> 6;
  int lm = lane & 15, quad = lane >> 4;
  int wm = w & 1, wn = w >> 1;
  int n0 = blockIdx.x * 128, m0 = blockIdx.y * 128;
  int lmx = lm & 3;

  int r0s = tid >> 2, c0s = ((tid & 3) ^ (r0s & 3)) * 16;
  int r1s = (tid + 256) >> 2, c1s = (((tid + 256) & 3) ^ (r1s & 3)) * 16;
  const char* saA0 = (const char*)(A  + (size_t)(m0 + r0s) * Ec) + c0s;
  const char* saA1 = (const char*)(A  + (size_t)(m0 + r1s) * Ec) + c1s;
  const char* saB0 = (const char*)(BT + (size_t)(n0 + r0s) * Ec) + c0s;
  const char* saB1 = (const char*)(BT + (size_t)(n0 + r1s) * Ec) + c1s;

  gl_lds16(saA0, (char*)As[0] + tid * 16);
  gl_lds16(saA1, (char*)As[0] + tid * 16 + 4096);
  gl_lds16(saB0, (char*)Bs[0] + tid * 16);
  gl_lds16(saB1, (char*)Bs[0] + tid * 16 + 4096);
  __syncthreads();

  f32x4 acc[4][4] = {};
  #pragma unroll 1
  for (int kt = 0; kt < 16; ++kt){
    int cur = kt & 1, nb = cur ^ 1;
    if (kt < 15){
      int k0 = (kt + 1) * 64;   // bytes
      gl_lds16(saA0 + k0, (char*)As[nb] + tid * 16);
      gl_lds16(saA1 + k0, (char*)As[nb] + tid * 16 + 4096);
      gl_lds16(saB0 + k0, (char*)Bs[nb] + tid * 16);
      gl_lds16(saB1 + k0, (char*)Bs[nb] + tid * 16 + 4096);
    }
    bf16x8 af[4], bfr[4];
    #pragma unroll
    for (int s = 0; s < 4; ++s)
      af[s]  = ldb8(As[cur] + ((wm * 64 + s * 16 + lm) * 4 + (quad ^ lmx)) * 8);
    #pragma unroll
    for (int t = 0; t < 4; ++t)
      bfr[t] = ldb8(Bs[cur] + ((wn * 64 + t * 16 + lm) * 4 + (quad ^ lmx)) * 8);
    #pragma unroll
    for (int s = 0; s < 4; ++s)
      #pragma unroll
      for (int t = 0; t < 4; ++t)
        acc[s][t] = mfma16(bfr[t], af[s], acc[s][t]);   // C^T orientation
    __syncthreads();
  }

  #pragma unroll
  for (int s = 0; s < 4; ++s){
    int row = m0 + wm * 64 + s * 16 + lm;
    #pragma unroll
    for (int t = 0; t < 4; ++t){
      int col = n0 + wn * 64 + t * 16 + quad * 4;
      float4 xr = *(const float4*)(x + (size_t)row * Ec + col);
      float4 o4 = {acc[s][t][0] + xr.x, acc[s][t][1] + xr.y,
                   acc[s][t][2] + xr.z, acc[s][t][3] + xr.w};
      *(float4*)(out + (size_t)row * Ec + col) = o4;
    }
  }
}

extern "C" void kernel_launch(void* const* d_in, const int* in_sizes, int n_in,
                              void* d_out, int out_size, void* d_ws, size_t ws_size,
                              hipStream_t stream){
  (void)in_sizes; (void)n_in; (void)out_size; (void)ws_size;
  const float* x        = (const float*)d_in[0];
  const float* w_uvqk   = (const float*)d_in[1];
  const float* b_uvqk   = (const float*)d_in[2];
  const float* ln_in_w  = (const float*)d_in[3];
  const float* ln_in_b  = (const float*)d_in[4];
  const float* ln_out_w = (const float*)d_in[5];
  const float* ln_out_b = (const float*)d_in[6];
  const float* w_proj   = (const float*)d_in[7];
  float* out = (float*)d_out;

  char* ws = (char*)d_ws;
  unsigned short* xn  = (unsigned short*)(ws + 0);          // 16 MB, reused as `par` later
  unsigned short* wuT = (unsigned short*)(ws + 16777216);   // 2 MB
  unsigned short* wpT = (unsigned short*)(ws + 18874368);   // 0.5 MB
  unsigned short* ub  = (unsigned short*)(ws + 19398656);   // 16 MB (bf16)
  unsigned short* qbf = (unsigned short*)(ws + 52953088);   // 16 MB
  unsigned short* kbf = (unsigned short*)(ws + 69730304);   // 16 MB
  unsigned short* vTt = (unsigned short*)(ws + 86507520);   // 16 MB
  unsigned short* att = (unsigned short*)(ws + 103284736);  // 16 MB (bf16)

  dim3 tb(32, 32);
  k_transpose_cast<<<dim3(N1c / 32, Ec / 32), tb, 0, stream>>>(w_uvqk, wuT, Ec, N1c);
  k_transpose_cast<<<dim3(Ec / 32, Ec / 32), tb, 0, stream>>>(w_proj, wpT, Ec, Ec);
  k_ln_in<<<Tc / 4, 256, 0, stream>>>(x, ln_in_w, ln_in_b, xn);
  k_gemm_uvqk<<<dim3(N1c / 128, Tc / 128), 256, 0, stream>>>(xn, wuT, b_uvqk, ub, vTt, qbf, kbf);
  k_attn<<<dim3(Bc * Hc, Sc / 64), 256, 0, stream>>>(qbf, kbf, vTt, att);
  k_ln_mul<<<Tc / 4, 256, 0, stream>>>(att, ln_out_w, ln_out_b, ub, xn);
  k_gemm_proj<<<dim3(Ec / 128, Tc / 128), 256, 0, stream>>>(xn, wpT, x, out);
}